// Round 1
// baseline (971.124 us; speedup 1.0000x reference)
//
#include <hip/hip_runtime.h>
#include <hip/hip_bf16.h>

// GIN x2 layers x2 branches + per-graph 9x9 gram einsum.
// Round 1: correctness-first fp32. Atomic scatter-add aggregation,
// LDS-tiled SIMT MLPs (no fp32 MFMA on CDNA4), LDS-staged einsum.

#define TM 32  // nodes per MLP block

// ---------------- edge aggregation: agg[dst] += h[src] -------------------
template<int F, int FPAD_LOG>
__global__ __launch_bounds__(256) void edge_agg_kernel(
    const int* __restrict__ src, const int* __restrict__ dst,
    const float* __restrict__ h, float* __restrict__ agg, int ecount)
{
    long long idx = (long long)blockIdx.x * 256 + threadIdx.x;
    int e = (int)(idx >> FPAD_LOG);
    int f = (int)(idx & ((1 << FPAD_LOG) - 1));
    if (e >= ecount) return;
    if ((F != (1 << FPAD_LOG)) && f >= F) return;
    int s = src[e], d = dst[e];
    unsafeAtomicAdd(&agg[(size_t)d * F + f], h[(size_t)s * F + f]);
}

// ---------------- MLP: out = relu((A+Agg) @ W1 + b1) @ W2 + b2 ----------
// Block: 256 threads, TM nodes. Activations transposed in LDS (pad +4 keeps
// float4 alignment of rows: row stride 36 floats = 144B, 16B-multiple).
template<int IND, int HID, int OUTD>
__global__ __launch_bounds__(256) void mlp_kernel(
    const float* __restrict__ A, const float* __restrict__ Agg,
    const float* __restrict__ W1, const float* __restrict__ B1,
    const float* __restrict__ W2, const float* __restrict__ B2,
    float* __restrict__ Out, int n_nodes)
{
    constexpr int LD = TM + 4;
    __shared__ float hs[IND][LD];   // input,  transposed [k][node]
    __shared__ float hm[HID][LD];   // hidden, transposed [k][node]
    const int tid = threadIdx.x;
    const int n0blk = blockIdx.x * TM;

    // stage input (A + Agg), transposed
    for (int idx = tid; idx < TM * IND; idx += 256) {
        int n = idx / IND, k = idx - n * IND;
        int gn = n0blk + n;
        float v = 0.f;
        if (gn < n_nodes) v = A[(size_t)gn * IND + k] + Agg[(size_t)gn * IND + k];
        hs[k][n] = v;
    }
    __syncthreads();

    // ---- stage 1: hm = relu(hs^T @ W1 + b1) ----
    {
        constexpr int CG = HID / 4;    // 32 col groups (4 cols each)
        constexpr int NG = 256 / CG;   // 8 node groups
        constexpr int NPT = TM / NG;   // 4 nodes per thread
        static_assert(NPT == 4, "stage1 mapping expects NPT==4");
        const int cg = tid % CG, ng = tid / CG;
        const int c0 = cg * 4, n0 = ng * NPT;
        float acc[4][4] = {};
        for (int k = 0; k < IND; ++k) {
            const float4 w = *(const float4*)&W1[k * HID + c0];
            const float4 h4 = *(const float4*)&hs[k][n0];
            const float hv[4] = {h4.x, h4.y, h4.z, h4.w};
            const float wv[4] = {w.x, w.y, w.z, w.w};
            #pragma unroll
            for (int i = 0; i < 4; ++i)
                #pragma unroll
                for (int j = 0; j < 4; ++j)
                    acc[i][j] += hv[i] * wv[j];
        }
        const float4 b = *(const float4*)&B1[c0];
        const float bv[4] = {b.x, b.y, b.z, b.w};
        #pragma unroll
        for (int j = 0; j < 4; ++j) {
            float4 st;
            st.x = fmaxf(acc[0][j] + bv[j], 0.f);
            st.y = fmaxf(acc[1][j] + bv[j], 0.f);
            st.z = fmaxf(acc[2][j] + bv[j], 0.f);
            st.w = fmaxf(acc[3][j] + bv[j], 0.f);
            *(float4*)&hm[c0 + j][n0] = st;
        }
    }
    __syncthreads();

    // ---- stage 2: out = hm^T @ W2 + b2 ----
    {
        constexpr int CG = OUTD / 4;
        constexpr int NG = 256 / CG;
        constexpr int NPT = TM / NG;   // 4 (OUTD=128) or 2 (OUTD=64)
        const int cg = tid % CG, ng = tid / CG;
        const int c0 = cg * 4, n0 = ng * NPT;
        float acc[NPT][4] = {};
        for (int k = 0; k < HID; ++k) {
            const float4 w = *(const float4*)&W2[k * OUTD + c0];
            const float wv[4] = {w.x, w.y, w.z, w.w};
            float hv[NPT];
            if constexpr (NPT == 4) {
                float4 h4 = *(const float4*)&hm[k][n0];
                hv[0] = h4.x; hv[1] = h4.y; hv[2] = h4.z; hv[3] = h4.w;
            } else {
                float2 h2 = *(const float2*)&hm[k][n0];
                hv[0] = h2.x; hv[1] = h2.y;
            }
            #pragma unroll
            for (int i = 0; i < NPT; ++i)
                #pragma unroll
                for (int j = 0; j < 4; ++j)
                    acc[i][j] += hv[i] * wv[j];
        }
        const float4 b = *(const float4*)&B2[c0];
        #pragma unroll
        for (int i = 0; i < NPT; ++i) {
            int gn = n0blk + n0 + i;
            if (gn < n_nodes) {
                float4 st;
                st.x = acc[i][0] + b.x;
                st.y = acc[i][1] + b.y;
                st.z = acc[i][2] + b.z;
                st.w = acc[i][3] + b.w;
                *(float4*)&Out[(size_t)gn * OUTD + c0] = st;
            }
        }
    }
}

// ---------------- per-graph 9x9 gram: out[g,i,j] = zs[g,i,:]·zt[g,j,:] ----
__global__ __launch_bounds__(128) void einsum9_kernel(
    const float* __restrict__ zs, const float* __restrict__ zt,
    float* __restrict__ out, int G)
{
    int g = blockIdx.x;
    if (g >= G) return;
    __shared__ float ss[9][68];
    __shared__ float tt[9][68];
    const int tid = threadIdx.x;
    for (int idx = tid; idx < 9 * 64; idx += 128) {
        int n = idx >> 6, k = idx & 63;
        ss[n][k] = zs[((size_t)g * 9 + n) * 64 + k];
        tt[n][k] = zt[((size_t)g * 9 + n) * 64 + k];
    }
    __syncthreads();
    if (tid < 81) {
        int i = tid / 9, j = tid - 9 * (tid / 9);
        float acc = 0.f;
        #pragma unroll
        for (int k = 0; k < 64; ++k) acc += ss[i][k] * tt[j][k];
        out[((size_t)g * 9 + i) * 9 + j] = acc;
    }
}

extern "C" void kernel_launch(void* const* d_in, const int* in_sizes, int n_in,
                              void* d_out, int out_size, void* d_ws, size_t ws_size,
                              hipStream_t stream)
{
    const float* x  = (const float*)d_in[0];
    const int*   ei = (const int*)d_in[1];
    const int N_ = in_sizes[0] / 30;
    const int E_ = in_sizes[1] / 2;
    const int* src = ei;
    const int* dst = ei + E_;

    const float* w1s = (const float*)d_in[2];
    const float* b1s = (const float*)d_in[3];
    const float* w2s = (const float*)d_in[4];
    const float* b2s = (const float*)d_in[5];
    const float* w3s = (const float*)d_in[6];
    const float* b3s = (const float*)d_in[7];
    const float* w4s = (const float*)d_in[8];
    const float* b4s = (const float*)d_in[9];
    const float* w1t = (const float*)d_in[10];
    const float* b1t = (const float*)d_in[11];
    const float* w2t = (const float*)d_in[12];
    const float* b2t = (const float*)d_in[13];
    const float* w3t = (const float*)d_in[14];
    const float* b3t = (const float*)d_in[15];
    const float* w4t = (const float*)d_in[16];
    const float* b4t = (const float*)d_in[17];

    float* ws = (float*)d_ws;
    size_t o = 0;
    float* agg1 = ws + o; o += (size_t)N_ * 30;
    float* z1s  = ws + o; o += (size_t)N_ * 128;
    float* z1t  = ws + o; o += (size_t)N_ * 128;
    float* agg2 = ws + o; o += (size_t)N_ * 128;  // shared: s consumed before t
    float* z2s  = ws + o; o += (size_t)N_ * 64;
    float* z2t  = ws + o; o += (size_t)N_ * 64;
    if (ws_size < o * sizeof(float)) return;  // workspace too small — bail

    const int nb = (N_ + TM - 1) / TM;

    // ---- layer 1 (agg over x shared between branches) ----
    hipMemsetAsync(agg1, 0, (size_t)N_ * 30 * sizeof(float), stream);
    {
        long long tot = (long long)E_ * 32;
        edge_agg_kernel<30, 5><<<(unsigned)((tot + 255) / 256), 256, 0, stream>>>(
            src, dst, x, agg1, E_);
    }
    mlp_kernel<30, 128, 128><<<nb, 256, 0, stream>>>(x, agg1, w1s, b1s, w2s, b2s, z1s, N_);
    mlp_kernel<30, 128, 128><<<nb, 256, 0, stream>>>(x, agg1, w1t, b1t, w2t, b2t, z1t, N_);

    // ---- layer 2, branch s ----
    hipMemsetAsync(agg2, 0, (size_t)N_ * 128 * sizeof(float), stream);
    {
        long long tot = (long long)E_ * 128;
        edge_agg_kernel<128, 7><<<(unsigned)((tot + 255) / 256), 256, 0, stream>>>(
            src, dst, z1s, agg2, E_);
    }
    mlp_kernel<128, 128, 64><<<nb, 256, 0, stream>>>(z1s, agg2, w3s, b3s, w4s, b4s, z2s, N_);

    // ---- layer 2, branch t (reuse agg2) ----
    hipMemsetAsync(agg2, 0, (size_t)N_ * 128 * sizeof(float), stream);
    {
        long long tot = (long long)E_ * 128;
        edge_agg_kernel<128, 7><<<(unsigned)((tot + 255) / 256), 256, 0, stream>>>(
            src, dst, z1t, agg2, E_);
    }
    mlp_kernel<128, 128, 64><<<nb, 256, 0, stream>>>(z1t, agg2, w3t, b3t, w4t, b4t, z2t, N_);

    // ---- per-graph 9x9 gram ----
    {
        int G = N_ / 9;
        einsum9_kernel<<<G, 128, 0, stream>>>(z2s, z2t, (float*)d_out, G);
    }
}

// Round 2
// 649.222 us; speedup vs baseline: 1.4958x; 1.4958x over previous
//
#include <hip/hip_runtime.h>
#include <hip/hip_bf16.h>

// GIN x2 layers x2 branches + per-graph 9x9 gram einsum.
// Round 2: CSR-gather aggregation (no fp32 atomics), fused dual-branch
// layer-1 MLP with in-kernel x-gather, TM=64 / 4x8 register-tiled MLPs,
// branch-concatenated activations so one 256-wide gather serves both branches.

// ---------------------------------------------------------------- CSR build
__global__ __launch_bounds__(256) void hist_kernel(
    const int* __restrict__ dst, int* __restrict__ deg, int E)
{
    int e = blockIdx.x * 256 + threadIdx.x;
    if (e < E) atomicAdd(&deg[dst[e]], 1);
}

__global__ __launch_bounds__(256) void blocksum_kernel(
    const int* __restrict__ deg, int* __restrict__ bsum, int N)
{
    __shared__ int sh[256];
    int i = blockIdx.x * 256 + threadIdx.x;
    sh[threadIdx.x] = (i < N) ? deg[i] : 0;
    __syncthreads();
    for (int off = 128; off > 0; off >>= 1) {
        if (threadIdx.x < off) sh[threadIdx.x] += sh[threadIdx.x + off];
        __syncthreads();
    }
    if (threadIdx.x == 0) bsum[blockIdx.x] = sh[0];
}

__global__ __launch_bounds__(1024) void scanblock_kernel(
    const int* __restrict__ bsum, int* __restrict__ boff, int nb)
{
    __shared__ int sh[1024];
    int t = threadIdx.x;
    int v = (t < nb) ? bsum[t] : 0;
    sh[t] = v;
    __syncthreads();
    for (int off = 1; off < 1024; off <<= 1) {
        int a = (t >= off) ? sh[t - off] : 0;
        __syncthreads();
        sh[t] += a;
        __syncthreads();
    }
    if (t < nb) boff[t] = sh[t] - v;   // exclusive
}

__global__ __launch_bounds__(256) void rowptr_kernel(
    const int* __restrict__ deg, const int* __restrict__ boff,
    int* __restrict__ rowptr, int N, int E)
{
    __shared__ int sh[256];
    int t = threadIdx.x;
    int i = blockIdx.x * 256 + t;
    int v = (i < N) ? deg[i] : 0;
    sh[t] = v;
    __syncthreads();
    for (int off = 1; off < 256; off <<= 1) {
        int a = (t >= off) ? sh[t - off] : 0;
        __syncthreads();
        sh[t] += a;
        __syncthreads();
    }
    if (i < N) rowptr[i] = boff[blockIdx.x] + sh[t] - v;
    if (i == 0) rowptr[N] = E;
}

__global__ __launch_bounds__(256) void scatter_kernel(
    const int* __restrict__ src, const int* __restrict__ dst,
    int* __restrict__ cursor, int* __restrict__ col, int E)
{
    int e = blockIdx.x * 256 + threadIdx.x;
    if (e < E) {
        int d = dst[e];
        int pos = atomicAdd(&cursor[d], 1);
        col[pos] = src[e];
    }
}

// --------------------------------------------- layer-2 aggregation (gather)
// One wave per node; lane l owns float4 l of the 256-wide concatenated row.
// Output includes the self term, so downstream MLP reads only this buffer.
__global__ __launch_bounds__(256) void gather256_kernel(
    const float* __restrict__ z1cat, const int* __restrict__ rowptr,
    const int* __restrict__ col, float* __restrict__ out, int N)
{
    int w = (blockIdx.x * 256 + threadIdx.x) >> 6;
    if (w >= N) return;
    int l = threadIdx.x & 63;
    const float4* base = (const float4*)z1cat;   // 64 float4 per row
    float4 acc = base[(size_t)w * 64 + l];       // self
    int b = rowptr[w], e = rowptr[w + 1];
    for (int i = b; i < e; ++i) {
        int s = col[i];
        float4 v = base[(size_t)s * 64 + l];
        acc.x += v.x; acc.y += v.y; acc.z += v.z; acc.w += v.w;
    }
    ((float4*)out)[(size_t)w * 64 + l] = acc;
}

// ------------------------------------------------- layer-1 MLP (dual branch)
// Stages h1 = x + sum_neighbors(x) via CSR gather (30 dims), then for each
// branch: hm = relu(h1@W1+b1); z1cat[:, br*128 : br*128+128] = hm@W2+b2.
// TM=64 nodes/block, 256 threads, 4 nodes x 8 cols per thread.
__global__ __launch_bounds__(256) void mlp1_kernel(
    const float* __restrict__ x, const int* __restrict__ rowptr,
    const int* __restrict__ col,
    const float* __restrict__ w1s, const float* __restrict__ b1s,
    const float* __restrict__ w2s, const float* __restrict__ b2s,
    const float* __restrict__ w1t, const float* __restrict__ b1t,
    const float* __restrict__ w2t, const float* __restrict__ b2t,
    float* __restrict__ z1cat, int N)
{
    __shared__ float hs[30][68];    // h1 transposed [k][node]
    __shared__ float hm[128][68];   // hidden transposed
    const int tid = threadIdx.x;
    const int n0blk = blockIdx.x * 64;

    // ---- stage h1 = x[n] + sum_{s->n} x[s], transposed into hs ----
    {
        const int sub = tid >> 5;       // 8 half-waves
        const int ln  = tid & 31;       // 32 lanes, 30 active
        for (int nn = sub; nn < 64; nn += 8) {
            int gn = n0blk + nn;
            float acc = 0.f;
            if (gn < N && ln < 30) {
                acc = x[(size_t)gn * 30 + ln];
                int b = rowptr[gn], e = rowptr[gn + 1];
                for (int i = b; i < e; ++i)
                    acc += x[(size_t)col[i] * 30 + ln];
            }
            if (ln < 30) hs[ln][nn] = acc;
        }
    }
    __syncthreads();

    const int cg = tid & 15, ng = tid >> 4;
    const int c0 = cg * 8, n0 = ng * 4;

    for (int br = 0; br < 2; ++br) {
        const float* W1 = br ? w1t : w1s;
        const float* B1 = br ? b1t : b1s;
        const float* W2 = br ? w2t : w2s;
        const float* B2 = br ? b2t : b2s;

        // ---- stage 1: hm = relu(hs^T @ W1 + b1) ----
        {
            float acc[4][8] = {};
            for (int k = 0; k < 30; ++k) {
                const float4 h4 = *(const float4*)&hs[k][n0];
                const float4 wa = *(const float4*)&W1[k * 128 + c0];
                const float4 wb = *(const float4*)&W1[k * 128 + c0 + 4];
                const float hv[4] = {h4.x, h4.y, h4.z, h4.w};
                const float wv[8] = {wa.x, wa.y, wa.z, wa.w, wb.x, wb.y, wb.z, wb.w};
                #pragma unroll
                for (int i = 0; i < 4; ++i)
                    #pragma unroll
                    for (int j = 0; j < 8; ++j)
                        acc[i][j] += hv[i] * wv[j];
            }
            const float4 ba = *(const float4*)&B1[c0];
            const float4 bb = *(const float4*)&B1[c0 + 4];
            const float bv[8] = {ba.x, ba.y, ba.z, ba.w, bb.x, bb.y, bb.z, bb.w};
            #pragma unroll
            for (int j = 0; j < 8; ++j) {
                float4 st;
                st.x = fmaxf(acc[0][j] + bv[j], 0.f);
                st.y = fmaxf(acc[1][j] + bv[j], 0.f);
                st.z = fmaxf(acc[2][j] + bv[j], 0.f);
                st.w = fmaxf(acc[3][j] + bv[j], 0.f);
                *(float4*)&hm[c0 + j][n0] = st;
            }
        }
        __syncthreads();

        // ---- stage 2: z1cat[:, br*128 + c] = hm^T @ W2 + b2 ----
        {
            float acc[4][8] = {};
            for (int k = 0; k < 128; ++k) {
                const float4 h4 = *(const float4*)&hm[k][n0];
                const float4 wa = *(const float4*)&W2[k * 128 + c0];
                const float4 wb = *(const float4*)&W2[k * 128 + c0 + 4];
                const float hv[4] = {h4.x, h4.y, h4.z, h4.w};
                const float wv[8] = {wa.x, wa.y, wa.z, wa.w, wb.x, wb.y, wb.z, wb.w};
                #pragma unroll
                for (int i = 0; i < 4; ++i)
                    #pragma unroll
                    for (int j = 0; j < 8; ++j)
                        acc[i][j] += hv[i] * wv[j];
            }
            const float4 ba = *(const float4*)&B2[c0];
            const float4 bb = *(const float4*)&B2[c0 + 4];
            #pragma unroll
            for (int i = 0; i < 4; ++i) {
                int gn = n0blk + n0 + i;
                if (gn < N) {
                    float4 s0, s1;
                    s0.x = acc[i][0] + ba.x; s0.y = acc[i][1] + ba.y;
                    s0.z = acc[i][2] + ba.z; s0.w = acc[i][3] + ba.w;
                    s1.x = acc[i][4] + bb.x; s1.y = acc[i][5] + bb.y;
                    s1.z = acc[i][6] + bb.z; s1.w = acc[i][7] + bb.w;
                    size_t rb = (size_t)gn * 256 + br * 128 + c0;
                    *(float4*)&z1cat[rb]     = s0;
                    *(float4*)&z1cat[rb + 4] = s1;
                }
            }
        }
        if (br == 0) __syncthreads();   // protect hm before branch t rewrites it
    }
}

// ------------------------------------------------- layer-2 MLP (per branch)
// A = agg2cat + br*128 (row stride 256, self already included).
// Out = z2cat + br*64 (row stride 128). K=128 staged in two 64-halves to
// keep LDS <= 64 KB/block.
__global__ __launch_bounds__(256) void mlp2_kernel(
    const float* __restrict__ A,
    const float* __restrict__ W1, const float* __restrict__ B1,
    const float* __restrict__ W2, const float* __restrict__ B2,
    float* __restrict__ Out, int N)
{
    __shared__ float hs[64][68];    // K-half transposed [k][node]
    __shared__ float hm[128][68];   // hidden transposed
    const int tid = threadIdx.x;
    const int n0blk = blockIdx.x * 64;
    const int cg = tid & 15, ng = tid >> 4;
    const int c0 = cg * 8, n0 = ng * 4;

    float acc[4][8] = {};
    for (int half = 0; half < 2; ++half) {
        if (half) __syncthreads();          // everyone done reading prev half
        for (int idx = tid; idx < 64 * 64; idx += 256) {
            int n = idx >> 6, k = idx & 63;
            int gn = n0blk + n;
            hs[k][n] = (gn < N) ? A[(size_t)gn * 256 + half * 64 + k] : 0.f;
        }
        __syncthreads();
        for (int kk = 0; kk < 64; ++kk) {
            int k = half * 64 + kk;
            const float4 h4 = *(const float4*)&hs[kk][n0];
            const float4 wa = *(const float4*)&W1[k * 128 + c0];
            const float4 wb = *(const float4*)&W1[k * 128 + c0 + 4];
            const float hv[4] = {h4.x, h4.y, h4.z, h4.w};
            const float wv[8] = {wa.x, wa.y, wa.z, wa.w, wb.x, wb.y, wb.z, wb.w};
            #pragma unroll
            for (int i = 0; i < 4; ++i)
                #pragma unroll
                for (int j = 0; j < 8; ++j)
                    acc[i][j] += hv[i] * wv[j];
        }
    }
    {
        const float4 ba = *(const float4*)&B1[c0];
        const float4 bb = *(const float4*)&B1[c0 + 4];
        const float bv[8] = {ba.x, ba.y, ba.z, ba.w, bb.x, bb.y, bb.z, bb.w};
        #pragma unroll
        for (int j = 0; j < 8; ++j) {
            float4 st;
            st.x = fmaxf(acc[0][j] + bv[j], 0.f);
            st.y = fmaxf(acc[1][j] + bv[j], 0.f);
            st.z = fmaxf(acc[2][j] + bv[j], 0.f);
            st.w = fmaxf(acc[3][j] + bv[j], 0.f);
            *(float4*)&hm[c0 + j][n0] = st;
        }
    }
    __syncthreads();

    // ---- stage 2: Out = hm^T @ W2 + b2 (64 cols -> 4 cols/thread) ----
    {
        const int cg2 = tid & 15, ng2 = tid >> 4;
        const int c02 = cg2 * 4, n02 = ng2 * 4;
        float acc2[4][4] = {};
        for (int k = 0; k < 128; ++k) {
            const float4 h4 = *(const float4*)&hm[k][n02];
            const float4 w  = *(const float4*)&W2[k * 64 + c02];
            const float hv[4] = {h4.x, h4.y, h4.z, h4.w};
            const float wv[4] = {w.x, w.y, w.z, w.w};
            #pragma unroll
            for (int i = 0; i < 4; ++i)
                #pragma unroll
                for (int j = 0; j < 4; ++j)
                    acc2[i][j] += hv[i] * wv[j];
        }
        const float4 b = *(const float4*)&B2[c02];
        #pragma unroll
        for (int i = 0; i < 4; ++i) {
            int gn = n0blk + n02 + i;
            if (gn < N) {
                float4 st;
                st.x = acc2[i][0] + b.x; st.y = acc2[i][1] + b.y;
                st.z = acc2[i][2] + b.z; st.w = acc2[i][3] + b.w;
                *(float4*)&Out[(size_t)gn * 128 + c02] = st;
            }
        }
    }
}

// ---------------- per-graph 9x9 gram from z2cat [N,128] (s=0..63,t=64..127)
__global__ __launch_bounds__(128) void einsum9_kernel(
    const float* __restrict__ z2cat, float* __restrict__ out, int G)
{
    int g = blockIdx.x;
    if (g >= G) return;
    __shared__ float ss[9][68];
    __shared__ float tt[9][68];
    const int tid = threadIdx.x;
    for (int idx = tid; idx < 9 * 64; idx += 128) {
        int n = idx >> 6, k = idx & 63;
        size_t row = (size_t)(g * 9 + n) * 128;
        ss[n][k] = z2cat[row + k];
        tt[n][k] = z2cat[row + 64 + k];
    }
    __syncthreads();
    if (tid < 81) {
        int i = tid / 9, j = tid - 9 * (tid / 9);
        float acc = 0.f;
        #pragma unroll
        for (int k = 0; k < 64; ++k) acc += ss[i][k] * tt[j][k];
        out[(size_t)g * 81 + i * 9 + j] = acc;
    }
}

extern "C" void kernel_launch(void* const* d_in, const int* in_sizes, int n_in,
                              void* d_out, int out_size, void* d_ws, size_t ws_size,
                              hipStream_t stream)
{
    const float* x  = (const float*)d_in[0];
    const int*   ei = (const int*)d_in[1];
    const int N_ = in_sizes[0] / 30;
    const int E_ = in_sizes[1] / 2;
    const int* src = ei;
    const int* dst = ei + E_;

    const float* w1s = (const float*)d_in[2];
    const float* b1s = (const float*)d_in[3];
    const float* w2s = (const float*)d_in[4];
    const float* b2s = (const float*)d_in[5];
    const float* w3s = (const float*)d_in[6];
    const float* b3s = (const float*)d_in[7];
    const float* w4s = (const float*)d_in[8];
    const float* b4s = (const float*)d_in[9];
    const float* w1t = (const float*)d_in[10];
    const float* b1t = (const float*)d_in[11];
    const float* w2t = (const float*)d_in[12];
    const float* b2t = (const float*)d_in[13];
    const float* w3t = (const float*)d_in[14];
    const float* b3t = (const float*)d_in[15];
    const float* w4t = (const float*)d_in[16];
    const float* b4t = (const float*)d_in[17];

    // ---- workspace layout (ints, then float4-aligned float region) ----
    int* deg    = (int*)d_ws;               // N
    int* rowptr = deg + N_;                 // N+1
    int* cursor = rowptr + N_ + 1;          // N
    int* bsum   = cursor + N_;              // 1024
    int* boff   = bsum + 1024;              // 1024
    int* col    = boff + 1024;              // E
    size_t int_count = (size_t)3 * N_ + 1 + 2048 + (size_t)E_;
    size_t foff = (int_count + 3) & ~(size_t)3;     // 16B align float region
    float* z1cat = (float*)d_ws + foff;             // [N,256] s||t
    float* agg2  = z1cat + (size_t)N_ * 256;        // [N,256] incl. self
    float* z2cat = z1cat;                           // overlays dead z1cat
    size_t need = (foff + (size_t)N_ * 256 * 2) * sizeof(float);
    if (ws_size < need) return;

    const int nbE   = (E_ + 255) / 256;
    const int nb256 = (N_ + 255) / 256;
    const int nb64  = (N_ + 63) / 64;
    if (nb256 > 1024) return;   // single-block scan capacity (N<=262144)

    // ---- CSR build ----
    hipMemsetAsync(deg, 0, (size_t)N_ * sizeof(int), stream);
    hist_kernel<<<nbE, 256, 0, stream>>>(dst, deg, E_);
    blocksum_kernel<<<nb256, 256, 0, stream>>>(deg, bsum, N_);
    scanblock_kernel<<<1, 1024, 0, stream>>>(bsum, boff, nb256);
    rowptr_kernel<<<nb256, 256, 0, stream>>>(deg, boff, rowptr, N_, E_);
    hipMemcpyAsync(cursor, rowptr, (size_t)N_ * sizeof(int),
                   hipMemcpyDeviceToDevice, stream);
    scatter_kernel<<<nbE, 256, 0, stream>>>(src, dst, cursor, col, E_);

    // ---- layer 1: both branches, x-gather fused into staging ----
    mlp1_kernel<<<nb64, 256, 0, stream>>>(x, rowptr, col,
        w1s, b1s, w2s, b2s, w1t, b1t, w2t, b2t, z1cat, N_);

    // ---- layer-2 aggregation: one 256-wide gather, self included ----
    gather256_kernel<<<(N_ * 64 + 255) / 256, 256, 0, stream>>>(
        z1cat, rowptr, col, agg2, N_);

    // ---- layer 2 MLPs (read agg2 slices, write z2cat slices) ----
    mlp2_kernel<<<nb64, 256, 0, stream>>>(agg2,       w3s, b3s, w4s, b4s,
                                          z2cat,      N_);
    mlp2_kernel<<<nb64, 256, 0, stream>>>(agg2 + 128, w3t, b3t, w4t, b4t,
                                          z2cat + 64, N_);

    // ---- per-graph 9x9 gram ----
    einsum9_kernel<<<N_ / 9, 128, 0, stream>>>(z2cat, (float*)d_out, N_ / 9);
}

// Round 3
// 371.670 us; speedup vs baseline: 2.6129x; 1.7468x over previous
//
#include <hip/hip_runtime.h>
#include <hip/hip_bf16.h>

// GIN x2 layers x2 branches + per-graph 9x9 gram einsum.
// Round 3: bf16 MFMA (16x16x32) for all MLP GEMMs, fp32 accumulate.
// Weights pre-packed into per-lane frag order; activations staged in LDS
// row-major bf16 (stride 40/136 -> <=2-way bank aliasing); bf16 z1/agg2
// halve the neighbor-gather traffic. CSR build unchanged from round 2.

typedef __attribute__((ext_vector_type(8))) short short8;
typedef __attribute__((ext_vector_type(4))) float f32x4;

__device__ inline unsigned short f2bf(float f) {
    union { float f; unsigned u; } v; v.f = f;
    unsigned r = v.u + 0x7fffu + ((v.u >> 16) & 1u);   // RNE
    return (unsigned short)(r >> 16);
}
__device__ inline float bflo(unsigned u) { return __uint_as_float(u << 16); }
__device__ inline float bfhi(unsigned u) { return __uint_as_float(u & 0xffff0000u); }
__device__ inline unsigned packbf(float a, float b) {
    return (unsigned)f2bf(a) | ((unsigned)f2bf(b) << 16);
}

// pack offsets (ushort units): [w1s][w2s][w3s][w4s][w1t][w2t][w3t][w4t]
#define W1S_OFF 0
#define W2S_OFF 4096
#define W3S_OFF 20480
#define W4S_OFF 36864
#define W1T_OFF 45056
#define W2T_OFF 49152
#define W3T_OFF 65536
#define W4T_OFF 81920
#define PACK_USHORTS 90112

// ---------------------------------------------------------------- CSR build
__global__ __launch_bounds__(256) void hist_kernel(
    const int* __restrict__ dst, int* __restrict__ deg, int E)
{
    int e = blockIdx.x * 256 + threadIdx.x;
    if (e < E) atomicAdd(&deg[dst[e]], 1);
}

__global__ __launch_bounds__(256) void blocksum_kernel(
    const int* __restrict__ deg, int* __restrict__ bsum, int N)
{
    __shared__ int sh[256];
    int i = blockIdx.x * 256 + threadIdx.x;
    sh[threadIdx.x] = (i < N) ? deg[i] : 0;
    __syncthreads();
    for (int off = 128; off > 0; off >>= 1) {
        if (threadIdx.x < off) sh[threadIdx.x] += sh[threadIdx.x + off];
        __syncthreads();
    }
    if (threadIdx.x == 0) bsum[blockIdx.x] = sh[0];
}

__global__ __launch_bounds__(1024) void scanblock_kernel(
    const int* __restrict__ bsum, int* __restrict__ boff, int nb)
{
    __shared__ int sh[1024];
    int t = threadIdx.x;
    int v = (t < nb) ? bsum[t] : 0;
    sh[t] = v;
    __syncthreads();
    for (int off = 1; off < 1024; off <<= 1) {
        int a = (t >= off) ? sh[t - off] : 0;
        __syncthreads();
        sh[t] += a;
        __syncthreads();
    }
    if (t < nb) boff[t] = sh[t] - v;   // exclusive
}

__global__ __launch_bounds__(256) void rowptr_kernel(
    const int* __restrict__ deg, const int* __restrict__ boff,
    int* __restrict__ rowptr, int N, int E)
{
    __shared__ int sh[256];
    int t = threadIdx.x;
    int i = blockIdx.x * 256 + t;
    int v = (i < N) ? deg[i] : 0;
    sh[t] = v;
    __syncthreads();
    for (int off = 1; off < 256; off <<= 1) {
        int a = (t >= off) ? sh[t - off] : 0;
        __syncthreads();
        sh[t] += a;
        __syncthreads();
    }
    if (i < N) rowptr[i] = boff[blockIdx.x] + sh[t] - v;
    if (i == 0) rowptr[N] = E;
}

__global__ __launch_bounds__(256) void scatter_kernel(
    const int* __restrict__ src, const int* __restrict__ dst,
    int* __restrict__ cursor, int* __restrict__ col, int E)
{
    int e = blockIdx.x * 256 + threadIdx.x;
    if (e < E) {
        int d = dst[e];
        int pos = atomicAdd(&cursor[d], 1);
        col[pos] = src[e];
    }
}

// ------------------------------------------------------------ weight packer
// B-frag order for 16x16x32 bf16 (m89/m91-verified): lane l holds
// B[k = kt*32 + (l>>4)*8 + j][n = ct*16 + (l&15)], j=0..7 contiguous.
// Tile index = ct*KT + kt; 512 ushort per tile; 16B per lane.
__global__ __launch_bounds__(64) void wpack_kernel(
    const float* w0, const float* w1, const float* w2, const float* w3,
    const float* w4, const float* w5, const float* w6, const float* w7,
    unsigned short* __restrict__ pack)
{
    const int prefix[9] = {0, 8, 40, 72, 88, 96, 128, 160, 176};
    const int KTa[8] = {1, 4, 4, 4, 1, 4, 4, 4};
    const int KRa[8] = {30, 128, 128, 128, 30, 128, 128, 128};
    const int Ca[8]  = {128, 128, 128, 64, 128, 128, 128, 64};
    const int DOFF[8] = {W1S_OFF, W2S_OFF, W3S_OFF, W4S_OFF,
                         W1T_OFF, W2T_OFF, W3T_OFF, W4T_OFF};
    const float* Ws[8] = {w0, w1, w2, w3, w4, w5, w6, w7};
    int bid = blockIdx.x;
    int mi = 0;
    while (mi < 7 && bid >= prefix[mi + 1]) ++mi;
    int lt = bid - prefix[mi];
    int kt = lt % KTa[mi], ct = lt / KTa[mi];
    const float* W = Ws[mi];
    int l = threadIdx.x;
    int n = ct * 16 + (l & 15);
    for (int j = 0; j < 8; ++j) {
        int k = kt * 32 + (l >> 4) * 8 + j;
        float v = (k < KRa[mi]) ? W[(size_t)k * Ca[mi] + n] : 0.f;
        pack[(size_t)DOFF[mi] + (size_t)lt * 512 + l * 8 + j] = f2bf(v);
    }
}

// ------------------------------------------------- layer-1 MLP (dual branch)
// 64 nodes/block, 4 waves. h1 = x + sum_neighbors(x) gathered fp32, cast bf16
// into hs[64][40]. Per branch: stage1 (K=32) -> hm[64][136], stage2 (K=128)
// -> transpose via hm -> coalesced bf16 store to z1cat[:, br*128..+128].
__global__ __launch_bounds__(256) void mlp1_kernel(
    const float* __restrict__ x, const int* __restrict__ rowptr,
    const int* __restrict__ col, const unsigned short* __restrict__ pack,
    const float* __restrict__ b1s, const float* __restrict__ b2s,
    const float* __restrict__ b1t, const float* __restrict__ b2t,
    unsigned short* __restrict__ z1cat, int N)
{
    __shared__ __align__(16) unsigned short hs[64 * 40];
    __shared__ __align__(16) unsigned short hm[64 * 136];
    const int tid = threadIdx.x;
    const int n0blk = blockIdx.x * 64;

    // ---- gather h1 (fp32), cast to bf16 into hs ----
    {
        const int sub = tid >> 5, ln = tid & 31;
        for (int nn = sub; nn < 64; nn += 8) {
            int gn = n0blk + nn;
            float acc = 0.f;
            if (gn < N && ln < 30) {
                acc = x[(size_t)gn * 30 + ln];
                int b = rowptr[gn], e = rowptr[gn + 1];
                for (int i = b; i < e; ++i)
                    acc += x[(size_t)col[i] * 30 + ln];
            }
            hs[nn * 40 + ln] = (ln < 30) ? f2bf(acc) : (unsigned short)0;
        }
    }
    __syncthreads();

    const int wv = tid >> 6, l = tid & 63, q = l >> 4, m = l & 15;

    for (int br = 0; br < 2; ++br) {
        const float* B1 = br ? b1t : b1s;
        const float* B2 = br ? b2t : b2s;
        const int w1off = br ? W1T_OFF : W1S_OFF;
        const int w2off = br ? W2T_OFF : W2S_OFF;

        // ---- stage 1: hm = relu(h1 @ W1 + b1), K=32 single MFMA ----
        {
            short8 a[4];
            #pragma unroll
            for (int nt = 0; nt < 4; ++nt)
                a[nt] = *(const short8*)&hs[(nt * 16 + m) * 40 + q * 8];
            #pragma unroll
            for (int ci = 0; ci < 2; ++ci) {
                int ct = wv * 2 + ci;
                short8 bf = *(const short8*)&pack[w1off + ((size_t)ct * 64 + l) * 8];
                float bias = B1[ct * 16 + m];
                #pragma unroll
                for (int nt = 0; nt < 4; ++nt) {
                    f32x4 acc = {0.f, 0.f, 0.f, 0.f};
                    acc = __builtin_amdgcn_mfma_f32_16x16x32_bf16(a[nt], bf, acc, 0, 0, 0);
                    #pragma unroll
                    for (int r = 0; r < 4; ++r) {
                        float v = fmaxf(acc[r] + bias, 0.f);
                        hm[(nt * 16 + q * 4 + r) * 136 + ct * 16 + m] = f2bf(v);
                    }
                }
            }
        }
        __syncthreads();

        // ---- stage 2: z1 = hm @ W2 + b2 (K=128), defer writeback ----
        f32x4 acc2[4][2];
        #pragma unroll
        for (int nt = 0; nt < 4; ++nt)
            #pragma unroll
            for (int ci = 0; ci < 2; ++ci)
                acc2[nt][ci] = (f32x4){0.f, 0.f, 0.f, 0.f};
        for (int nt = 0; nt < 4; ++nt) {
            short8 a[4];
            #pragma unroll
            for (int kt = 0; kt < 4; ++kt)
                a[kt] = *(const short8*)&hm[(nt * 16 + m) * 136 + kt * 32 + q * 8];
            #pragma unroll
            for (int ci = 0; ci < 2; ++ci) {
                int ct = wv * 2 + ci;
                #pragma unroll
                for (int kt = 0; kt < 4; ++kt) {
                    short8 bf = *(const short8*)&pack[w2off + ((size_t)(ct * 4 + kt) * 64 + l) * 8];
                    acc2[nt][ci] = __builtin_amdgcn_mfma_f32_16x16x32_bf16(a[kt], bf, acc2[nt][ci], 0, 0, 0);
                }
            }
        }
        __syncthreads();   // all hm A-frag reads complete
        #pragma unroll
        for (int ci = 0; ci < 2; ++ci) {
            int ct = wv * 2 + ci;
            float bias = B2[ct * 16 + m];
            #pragma unroll
            for (int nt = 0; nt < 4; ++nt)
                #pragma unroll
                for (int r = 0; r < 4; ++r)
                    hm[(nt * 16 + q * 4 + r) * 136 + ct * 16 + m] =
                        f2bf(acc2[nt][ci][r] + bias);
        }
        __syncthreads();
        // coalesced copy-out: 64 rows x 128 bf16
        for (int c = tid; c < 1024; c += 256) {
            int row = c >> 4, off = c & 15;
            int gn = n0blk + row;
            if (gn < N) {
                short8 v = *(const short8*)&hm[row * 136 + off * 8];
                *(short8*)&z1cat[(size_t)gn * 256 + br * 128 + off * 8] = v;
            }
        }
        __syncthreads();   // before branch t rewrites hm
    }
}

// --------------------------------------------- layer-2 aggregation (gather)
// One wave per node; lane owns 8B (4 bf16) of the 256-wide row. fp32 sums.
__global__ __launch_bounds__(256) void gather256_kernel(
    const unsigned short* __restrict__ z1, const int* __restrict__ rowptr,
    const int* __restrict__ col, unsigned short* __restrict__ agg2, int N)
{
    int gid = blockIdx.x * 256 + threadIdx.x;
    int w = gid >> 6;
    if (w >= N) return;
    int l = gid & 63;
    const uint2* base = (const uint2*)z1;        // 64 uint2 per row
    uint2 s = base[(size_t)w * 64 + l];          // self
    float a0 = bflo(s.x), a1 = bfhi(s.x), a2 = bflo(s.y), a3 = bfhi(s.y);
    int b = rowptr[w], e = rowptr[w + 1];
    for (int i = b; i < e; ++i) {
        uint2 v = base[(size_t)col[i] * 64 + l];
        a0 += bflo(v.x); a1 += bfhi(v.x); a2 += bflo(v.y); a3 += bfhi(v.y);
    }
    uint2 o; o.x = packbf(a0, a1); o.y = packbf(a2, a3);
    ((uint2*)agg2)[(size_t)w * 64 + l] = o;
}

// ------------------------------------------------- layer-2 MLP (per branch)
// aggs = agg2 + br*128 (row stride 256 bf16, self included).
// out  = z2cat + br*64 (row stride 128 fp32).
__global__ __launch_bounds__(256) void mlp2_kernel(
    const unsigned short* __restrict__ aggs,
    const unsigned short* __restrict__ pack, int w1off, int w2off,
    const float* __restrict__ B1, const float* __restrict__ B2,
    float* __restrict__ out, int N)
{
    __shared__ __align__(16) unsigned short hs[64 * 136];
    __shared__ __align__(16) unsigned short hm[64 * 136];
    const int tid = threadIdx.x;
    const int n0blk = blockIdx.x * 64;

    // ---- stage input slice into hs ----
    for (int c = tid; c < 1024; c += 256) {
        int row = c >> 4, off = c & 15;
        int gn = n0blk + row;
        short8 v = {0, 0, 0, 0, 0, 0, 0, 0};
        if (gn < N) v = *(const short8*)&aggs[(size_t)gn * 256 + off * 8];
        *(short8*)&hs[row * 136 + off * 8] = v;
    }
    __syncthreads();

    const int wv = tid >> 6, l = tid & 63, q = l >> 4, m = l & 15;

    // ---- stage 1: hm = relu(hs @ W3 + b3), K=128 ----
    for (int nt = 0; nt < 4; ++nt) {
        short8 a[4];
        #pragma unroll
        for (int kt = 0; kt < 4; ++kt)
            a[kt] = *(const short8*)&hs[(nt * 16 + m) * 136 + kt * 32 + q * 8];
        #pragma unroll
        for (int ci = 0; ci < 2; ++ci) {
            int ct = wv * 2 + ci;
            f32x4 acc = {0.f, 0.f, 0.f, 0.f};
            #pragma unroll
            for (int kt = 0; kt < 4; ++kt) {
                short8 bf = *(const short8*)&pack[w1off + ((size_t)(ct * 4 + kt) * 64 + l) * 8];
                acc = __builtin_amdgcn_mfma_f32_16x16x32_bf16(a[kt], bf, acc, 0, 0, 0);
            }
            float bias = B1[ct * 16 + m];
            #pragma unroll
            for (int r = 0; r < 4; ++r) {
                float v = fmaxf(acc[r] + bias, 0.f);
                hm[(nt * 16 + q * 4 + r) * 136 + ct * 16 + m] = f2bf(v);
            }
        }
    }
    __syncthreads();

    // ---- stage 2: out = hm @ W4 + b4, C=64 (one col-tile per wave) ----
    {
        int ct = wv;
        float bias = B2[ct * 16 + m];
        for (int nt = 0; nt < 4; ++nt) {
            short8 a[4];
            #pragma unroll
            for (int kt = 0; kt < 4; ++kt)
                a[kt] = *(const short8*)&hm[(nt * 16 + m) * 136 + kt * 32 + q * 8];
            f32x4 acc = {0.f, 0.f, 0.f, 0.f};
            #pragma unroll
            for (int kt = 0; kt < 4; ++kt) {
                short8 bf = *(const short8*)&pack[w2off + ((size_t)(ct * 4 + kt) * 64 + l) * 8];
                acc = __builtin_amdgcn_mfma_f32_16x16x32_bf16(a[kt], bf, acc, 0, 0, 0);
            }
            #pragma unroll
            for (int r = 0; r < 4; ++r) {
                int gn = n0blk + nt * 16 + q * 4 + r;
                if (gn < N) out[(size_t)gn * 128 + ct * 16 + m] = acc[r] + bias;
            }
        }
    }
}

// ---------------- per-graph 9x9 gram from z2cat [N,128] (s=0..63,t=64..127)
__global__ __launch_bounds__(128) void einsum9_kernel(
    const float* __restrict__ z2cat, float* __restrict__ out, int G)
{
    int g = blockIdx.x;
    if (g >= G) return;
    __shared__ float ss[9][68];
    __shared__ float tt[9][68];
    const int tid = threadIdx.x;
    for (int idx = tid; idx < 9 * 64; idx += 128) {
        int n = idx >> 6, k = idx & 63;
        size_t row = (size_t)(g * 9 + n) * 128;
        ss[n][k] = z2cat[row + k];
        tt[n][k] = z2cat[row + 64 + k];
    }
    __syncthreads();
    if (tid < 81) {
        int i = tid / 9, j = tid - 9 * (tid / 9);
        float acc = 0.f;
        #pragma unroll
        for (int k = 0; k < 64; ++k) acc += ss[i][k] * tt[j][k];
        out[(size_t)g * 81 + i * 9 + j] = acc;
    }
}

extern "C" void kernel_launch(void* const* d_in, const int* in_sizes, int n_in,
                              void* d_out, int out_size, void* d_ws, size_t ws_size,
                              hipStream_t stream)
{
    const float* x  = (const float*)d_in[0];
    const int*   ei = (const int*)d_in[1];
    const int N_ = in_sizes[0] / 30;
    const int E_ = in_sizes[1] / 2;
    const int* src = ei;
    const int* dst = ei + E_;

    const float* w1s = (const float*)d_in[2];
    const float* b1s = (const float*)d_in[3];
    const float* w2s = (const float*)d_in[4];
    const float* b2s = (const float*)d_in[5];
    const float* w3s = (const float*)d_in[6];
    const float* b3s = (const float*)d_in[7];
    const float* w4s = (const float*)d_in[8];
    const float* b4s = (const float*)d_in[9];
    const float* w1t = (const float*)d_in[10];
    const float* b1t = (const float*)d_in[11];
    const float* w2t = (const float*)d_in[12];
    const float* b2t = (const float*)d_in[13];
    const float* w3t = (const float*)d_in[14];
    const float* b3t = (const float*)d_in[15];
    const float* w4t = (const float*)d_in[16];
    const float* b4t = (const float*)d_in[17];

    // ---- workspace layout ----
    int* deg    = (int*)d_ws;               // N
    int* rowptr = deg + N_;                 // N+1
    int* cursor = rowptr + N_ + 1;          // N
    int* bsum   = cursor + N_;              // 1024
    int* boff   = bsum + 1024;              // 1024
    int* col    = boff + 1024;              // E
    size_t int_bytes = ((size_t)3 * N_ + 1 + 2048 + (size_t)E_) * sizeof(int);
    size_t pb = (int_bytes + 15) & ~(size_t)15;
    unsigned short* packu = (unsigned short*)((char*)d_ws + pb);
    unsigned short* z1cat = packu + PACK_USHORTS;         // [N,256] bf16 s||t
    unsigned short* agg2  = z1cat + (size_t)N_ * 256;     // [N,256] bf16 incl self
    float* z2cat = (float*)(agg2 + (size_t)N_ * 256);     // [N,128] fp32 s||t
    size_t need = pb + (size_t)PACK_USHORTS * 2
                + (size_t)N_ * 256 * 2 * 2 + (size_t)N_ * 128 * 4;
    if (ws_size < need) return;

    const int nbE   = (E_ + 255) / 256;
    const int nb256 = (N_ + 255) / 256;
    const int nb64  = (N_ + 63) / 64;
    if (nb256 > 1024) return;   // single-block scan capacity

    // ---- weight packing (independent) ----
    wpack_kernel<<<176, 64, 0, stream>>>(w1s, w2s, w3s, w4s,
                                         w1t, w2t, w3t, w4t, packu);

    // ---- CSR build ----
    hipMemsetAsync(deg, 0, (size_t)N_ * sizeof(int), stream);
    hist_kernel<<<nbE, 256, 0, stream>>>(dst, deg, E_);
    blocksum_kernel<<<nb256, 256, 0, stream>>>(deg, bsum, N_);
    scanblock_kernel<<<1, 1024, 0, stream>>>(bsum, boff, nb256);
    rowptr_kernel<<<nb256, 256, 0, stream>>>(deg, boff, rowptr, N_, E_);
    hipMemcpyAsync(cursor, rowptr, (size_t)N_ * sizeof(int),
                   hipMemcpyDeviceToDevice, stream);
    scatter_kernel<<<nbE, 256, 0, stream>>>(src, dst, cursor, col, E_);

    // ---- layer 1: both branches (MFMA), writes bf16 z1cat ----
    mlp1_kernel<<<nb64, 256, 0, stream>>>(x, rowptr, col, packu,
        b1s, b2s, b1t, b2t, z1cat, N_);

    // ---- layer-2 aggregation: one 256-wide bf16 gather, self included ----
    gather256_kernel<<<(N_ * 64 + 255) / 256, 256, 0, stream>>>(
        z1cat, rowptr, col, agg2, N_);

    // ---- layer 2 MLPs (MFMA) ----
    mlp2_kernel<<<nb64, 256, 0, stream>>>(agg2,       packu, W3S_OFF, W4S_OFF,
                                          b3s, b4s, z2cat,      N_);
    mlp2_kernel<<<nb64, 256, 0, stream>>>(agg2 + 128, packu, W3T_OFF, W4T_OFF,
                                          b3t, b4t, z2cat + 64, N_);

    // ---- per-graph 9x9 gram ----
    einsum9_kernel<<<N_ / 9, 128, 0, stream>>>(z2cat, (float*)d_out, N_ / 9);
}

// Round 4
// 331.583 us; speedup vs baseline: 2.9288x; 1.1209x over previous
//
#include <hip/hip_runtime.h>
#include <hip/hip_bf16.h>

// GIN x2 layers x2 branches + per-graph 9x9 gram einsum.
// Round 4: decoupled high-TLP layer-1 gather (gather30), fused dual-branch
// layer-2 MLP, cursor folded into rowptr. MFMA paths unchanged from round 3
// (numerics bit-identical: absmax must stay 14.5).

typedef __attribute__((ext_vector_type(8))) short short8;
typedef __attribute__((ext_vector_type(4))) float f32x4;

__device__ inline unsigned short f2bf(float f) {
    union { float f; unsigned u; } v; v.f = f;
    unsigned r = v.u + 0x7fffu + ((v.u >> 16) & 1u);   // RNE
    return (unsigned short)(r >> 16);
}
__device__ inline float bflo(unsigned u) { return __uint_as_float(u << 16); }
__device__ inline float bfhi(unsigned u) { return __uint_as_float(u & 0xffff0000u); }
__device__ inline unsigned packbf(float a, float b) {
    return (unsigned)f2bf(a) | ((unsigned)f2bf(b) << 16);
}

// pack offsets (ushort units): [w1s][w2s][w3s][w4s][w1t][w2t][w3t][w4t]
#define W1S_OFF 0
#define W2S_OFF 4096
#define W3S_OFF 20480
#define W4S_OFF 36864
#define W1T_OFF 45056
#define W2T_OFF 49152
#define W3T_OFF 65536
#define W4T_OFF 81920
#define PACK_USHORTS 90112

// ---------------------------------------------------------------- CSR build
__global__ __launch_bounds__(256) void hist_kernel(
    const int* __restrict__ dst, int* __restrict__ deg, int E)
{
    int e = blockIdx.x * 256 + threadIdx.x;
    if (e < E) atomicAdd(&deg[dst[e]], 1);
}

__global__ __launch_bounds__(256) void blocksum_kernel(
    const int* __restrict__ deg, int* __restrict__ bsum, int N)
{
    __shared__ int sh[256];
    int i = blockIdx.x * 256 + threadIdx.x;
    sh[threadIdx.x] = (i < N) ? deg[i] : 0;
    __syncthreads();
    for (int off = 128; off > 0; off >>= 1) {
        if (threadIdx.x < off) sh[threadIdx.x] += sh[threadIdx.x + off];
        __syncthreads();
    }
    if (threadIdx.x == 0) bsum[blockIdx.x] = sh[0];
}

__global__ __launch_bounds__(1024) void scanblock_kernel(
    const int* __restrict__ bsum, int* __restrict__ boff, int nb)
{
    __shared__ int sh[1024];
    int t = threadIdx.x;
    int v = (t < nb) ? bsum[t] : 0;
    sh[t] = v;
    __syncthreads();
    for (int off = 1; off < 1024; off <<= 1) {
        int a = (t >= off) ? sh[t - off] : 0;
        __syncthreads();
        sh[t] += a;
        __syncthreads();
    }
    if (t < nb) boff[t] = sh[t] - v;   // exclusive
}

__global__ __launch_bounds__(256) void rowptr_kernel(
    const int* __restrict__ deg, const int* __restrict__ boff,
    int* __restrict__ rowptr, int* __restrict__ cursor, int N, int E)
{
    __shared__ int sh[256];
    int t = threadIdx.x;
    int i = blockIdx.x * 256 + t;
    int v = (i < N) ? deg[i] : 0;
    sh[t] = v;
    __syncthreads();
    for (int off = 1; off < 256; off <<= 1) {
        int a = (t >= off) ? sh[t - off] : 0;
        __syncthreads();
        sh[t] += a;
        __syncthreads();
    }
    if (i < N) {
        int r = boff[blockIdx.x] + sh[t] - v;
        rowptr[i] = r;
        cursor[i] = r;
    }
    if (i == 0) rowptr[N] = E;
}

__global__ __launch_bounds__(256) void scatter_kernel(
    const int* __restrict__ src, const int* __restrict__ dst,
    int* __restrict__ cursor, int* __restrict__ col, int E)
{
    int e = blockIdx.x * 256 + threadIdx.x;
    if (e < E) {
        int d = dst[e];
        int pos = atomicAdd(&cursor[d], 1);
        col[pos] = src[e];
    }
}

// ------------------------------------------------------------ weight packer
// B-frag order for 16x16x32 bf16 (m89/m91-verified): lane l holds
// B[k = kt*32 + (l>>4)*8 + j][n = ct*16 + (l&15)], j=0..7 contiguous.
__global__ __launch_bounds__(64) void wpack_kernel(
    const float* w0, const float* w1, const float* w2, const float* w3,
    const float* w4, const float* w5, const float* w6, const float* w7,
    unsigned short* __restrict__ pack)
{
    const int prefix[9] = {0, 8, 40, 72, 88, 96, 128, 160, 176};
    const int KTa[8] = {1, 4, 4, 4, 1, 4, 4, 4};
    const int KRa[8] = {30, 128, 128, 128, 30, 128, 128, 128};
    const int Ca[8]  = {128, 128, 128, 64, 128, 128, 128, 64};
    const int DOFF[8] = {W1S_OFF, W2S_OFF, W3S_OFF, W4S_OFF,
                         W1T_OFF, W2T_OFF, W3T_OFF, W4T_OFF};
    const float* Ws[8] = {w0, w1, w2, w3, w4, w5, w6, w7};
    int bid = blockIdx.x;
    int mi = 0;
    while (mi < 7 && bid >= prefix[mi + 1]) ++mi;
    int lt = bid - prefix[mi];
    int kt = lt % KTa[mi], ct = lt / KTa[mi];
    const float* W = Ws[mi];
    int l = threadIdx.x;
    int n = ct * 16 + (l & 15);
    for (int j = 0; j < 8; ++j) {
        int k = kt * 32 + (l >> 4) * 8 + j;
        float v = (k < KRa[mi]) ? W[(size_t)k * Ca[mi] + n] : 0.f;
        pack[(size_t)DOFF[mi] + (size_t)lt * 512 + l * 8 + j] = f2bf(v);
    }
}

// ------------------------------------------- layer-1 aggregation (gather)
// One 32-lane group per node: h1[n] = bf16(x[n] + sum_{s->n} x[s]).
// Massive TLP hides the col->x dependent-load chain.
__global__ __launch_bounds__(256) void gather30_kernel(
    const float* __restrict__ x, const int* __restrict__ rowptr,
    const int* __restrict__ col, unsigned short* __restrict__ h1, int N)
{
    int gid = blockIdx.x * 256 + threadIdx.x;
    int node = gid >> 5;
    if (node >= N) return;
    int ln = gid & 31;
    float acc = (ln < 30) ? x[(size_t)node * 30 + ln] : 0.f;
    int b = rowptr[node], e = rowptr[node + 1];
    for (int i = b; i < e; ++i) {
        int s = col[i];
        if (ln < 30) acc += x[(size_t)s * 30 + ln];
    }
    h1[(size_t)node * 32 + ln] = (ln < 30) ? f2bf(acc) : (unsigned short)0;
}

// ------------------------------------------------- layer-1 MLP (dual branch)
// 64 nodes/block, 4 waves. Stages h1 bf16 coalesced; per branch:
// stage1 (K=32) -> hm, stage2 (K=128) -> bf16 z1cat slice.
__global__ __launch_bounds__(256) void mlp1_kernel(
    const unsigned short* __restrict__ h1, const unsigned short* __restrict__ pack,
    const float* __restrict__ b1s, const float* __restrict__ b2s,
    const float* __restrict__ b1t, const float* __restrict__ b2t,
    unsigned short* __restrict__ z1cat, int N)
{
    __shared__ __align__(16) unsigned short hs[64 * 40];
    __shared__ __align__(16) unsigned short hm[64 * 136];
    const int tid = threadIdx.x;
    const int n0blk = blockIdx.x * 64;

    // ---- stage h1 rows (32 bf16 each), coalesced 16B/thread ----
    {
        int row = tid >> 2, off = tid & 3;
        int gn = n0blk + row;
        short8 v = {0, 0, 0, 0, 0, 0, 0, 0};
        if (gn < N) v = *(const short8*)&h1[(size_t)gn * 32 + off * 8];
        *(short8*)&hs[row * 40 + off * 8] = v;
    }
    __syncthreads();

    const int wv = tid >> 6, l = tid & 63, q = l >> 4, m = l & 15;

    for (int br = 0; br < 2; ++br) {
        const float* B1 = br ? b1t : b1s;
        const float* B2 = br ? b2t : b2s;
        const int w1off = br ? W1T_OFF : W1S_OFF;
        const int w2off = br ? W2T_OFF : W2S_OFF;

        // ---- stage 1: hm = relu(h1 @ W1 + b1), K=32 single MFMA ----
        {
            short8 a[4];
            #pragma unroll
            for (int nt = 0; nt < 4; ++nt)
                a[nt] = *(const short8*)&hs[(nt * 16 + m) * 40 + q * 8];
            #pragma unroll
            for (int ci = 0; ci < 2; ++ci) {
                int ct = wv * 2 + ci;
                short8 bf = *(const short8*)&pack[w1off + ((size_t)ct * 64 + l) * 8];
                float bias = B1[ct * 16 + m];
                #pragma unroll
                for (int nt = 0; nt < 4; ++nt) {
                    f32x4 acc = {0.f, 0.f, 0.f, 0.f};
                    acc = __builtin_amdgcn_mfma_f32_16x16x32_bf16(a[nt], bf, acc, 0, 0, 0);
                    #pragma unroll
                    for (int r = 0; r < 4; ++r) {
                        float v = fmaxf(acc[r] + bias, 0.f);
                        hm[(nt * 16 + q * 4 + r) * 136 + ct * 16 + m] = f2bf(v);
                    }
                }
            }
        }
        __syncthreads();

        // ---- stage 2: z1 = hm @ W2 + b2 (K=128), defer writeback ----
        f32x4 acc2[4][2];
        #pragma unroll
        for (int nt = 0; nt < 4; ++nt)
            #pragma unroll
            for (int ci = 0; ci < 2; ++ci)
                acc2[nt][ci] = (f32x4){0.f, 0.f, 0.f, 0.f};
        for (int nt = 0; nt < 4; ++nt) {
            short8 a[4];
            #pragma unroll
            for (int kt = 0; kt < 4; ++kt)
                a[kt] = *(const short8*)&hm[(nt * 16 + m) * 136 + kt * 32 + q * 8];
            #pragma unroll
            for (int ci = 0; ci < 2; ++ci) {
                int ct = wv * 2 + ci;
                #pragma unroll
                for (int kt = 0; kt < 4; ++kt) {
                    short8 bf = *(const short8*)&pack[w2off + ((size_t)(ct * 4 + kt) * 64 + l) * 8];
                    acc2[nt][ci] = __builtin_amdgcn_mfma_f32_16x16x32_bf16(a[kt], bf, acc2[nt][ci], 0, 0, 0);
                }
            }
        }
        __syncthreads();   // all hm A-frag reads complete
        #pragma unroll
        for (int ci = 0; ci < 2; ++ci) {
            int ct = wv * 2 + ci;
            float bias = B2[ct * 16 + m];
            #pragma unroll
            for (int nt = 0; nt < 4; ++nt)
                #pragma unroll
                for (int r = 0; r < 4; ++r)
                    hm[(nt * 16 + q * 4 + r) * 136 + ct * 16 + m] =
                        f2bf(acc2[nt][ci][r] + bias);
        }
        __syncthreads();
        // coalesced copy-out: 64 rows x 128 bf16
        for (int c = tid; c < 1024; c += 256) {
            int row = c >> 4, off = c & 15;
            int gn = n0blk + row;
            if (gn < N) {
                short8 v = *(const short8*)&hm[row * 136 + off * 8];
                *(short8*)&z1cat[(size_t)gn * 256 + br * 128 + off * 8] = v;
            }
        }
        __syncthreads();   // before branch t rewrites hm
    }
}

// --------------------------------------------- layer-2 aggregation (gather)
// One wave per node; lane owns 8B (4 bf16) of the 256-wide row. fp32 sums.
__global__ __launch_bounds__(256) void gather256_kernel(
    const unsigned short* __restrict__ z1, const int* __restrict__ rowptr,
    const int* __restrict__ col, unsigned short* __restrict__ agg2, int N)
{
    int gid = blockIdx.x * 256 + threadIdx.x;
    int w = gid >> 6;
    if (w >= N) return;
    int l = gid & 63;
    const uint2* base = (const uint2*)z1;        // 64 uint2 per row
    uint2 s = base[(size_t)w * 64 + l];          // self
    float a0 = bflo(s.x), a1 = bfhi(s.x), a2 = bflo(s.y), a3 = bfhi(s.y);
    int b = rowptr[w], e = rowptr[w + 1];
    for (int i = b; i < e; ++i) {
        uint2 v = base[(size_t)col[i] * 64 + l];
        a0 += bflo(v.x); a1 += bfhi(v.x); a2 += bflo(v.y); a3 += bfhi(v.y);
    }
    uint2 o; o.x = packbf(a0, a1); o.y = packbf(a2, a3);
    ((uint2*)agg2)[(size_t)w * 64 + l] = o;
}

// --------------------------------------- layer-2 MLP (both branches fused)
// Stages full 256-wide agg2 row once; branch s uses cols 0..127, branch t
// cols 128..255. Writes z2cat [N,128] fp32 (s cols 0..63, t cols 64..127).
__global__ __launch_bounds__(256) void mlp2_kernel(
    const unsigned short* __restrict__ agg2,
    const unsigned short* __restrict__ pack,
    const float* __restrict__ b3s, const float* __restrict__ b4s,
    const float* __restrict__ b3t, const float* __restrict__ b4t,
    float* __restrict__ z2cat, int N)
{
    __shared__ __align__(16) unsigned short hs[64 * 264];
    __shared__ __align__(16) unsigned short hm[64 * 136];
    const int tid = threadIdx.x;
    const int n0blk = blockIdx.x * 64;

    // ---- stage full rows: 64 x 256 bf16, 16B/thread x 8 ----
    for (int c = tid; c < 2048; c += 256) {
        int row = c >> 5, off = c & 31;
        int gn = n0blk + row;
        short8 v = {0, 0, 0, 0, 0, 0, 0, 0};
        if (gn < N) v = *(const short8*)&agg2[(size_t)gn * 256 + off * 8];
        *(short8*)&hs[row * 264 + off * 8] = v;
    }
    __syncthreads();

    const int wv = tid >> 6, l = tid & 63, q = l >> 4, m = l & 15;

    for (int br = 0; br < 2; ++br) {
        const int w1off = br ? W3T_OFF : W3S_OFF;
        const int w2off = br ? W4T_OFF : W4S_OFF;
        const float* B1 = br ? b3t : b3s;
        const float* B2 = br ? b4t : b4s;
        if (br) __syncthreads();   // br0 stage2 hm reads done before rewrite

        // ---- stage 1: hm = relu(hs[:, br*128..] @ W3 + b3), K=128 ----
        for (int nt = 0; nt < 4; ++nt) {
            short8 a[4];
            #pragma unroll
            for (int kt = 0; kt < 4; ++kt)
                a[kt] = *(const short8*)&hs[(nt * 16 + m) * 264 + br * 128 + kt * 32 + q * 8];
            #pragma unroll
            for (int ci = 0; ci < 2; ++ci) {
                int ct = wv * 2 + ci;
                f32x4 acc = {0.f, 0.f, 0.f, 0.f};
                #pragma unroll
                for (int kt = 0; kt < 4; ++kt) {
                    short8 bf = *(const short8*)&pack[w1off + ((size_t)(ct * 4 + kt) * 64 + l) * 8];
                    acc = __builtin_amdgcn_mfma_f32_16x16x32_bf16(a[kt], bf, acc, 0, 0, 0);
                }
                float bias = B1[ct * 16 + m];
                #pragma unroll
                for (int r = 0; r < 4; ++r) {
                    float v = fmaxf(acc[r] + bias, 0.f);
                    hm[(nt * 16 + q * 4 + r) * 136 + ct * 16 + m] = f2bf(v);
                }
            }
        }
        __syncthreads();

        // ---- stage 2: z2cat slice = hm @ W4 + b4 (64 cols, 1 ct/wave) ----
        {
            int ct = wv;
            float bias = B2[ct * 16 + m];
            for (int nt = 0; nt < 4; ++nt) {
                short8 a[4];
                #pragma unroll
                for (int kt = 0; kt < 4; ++kt)
                    a[kt] = *(const short8*)&hm[(nt * 16 + m) * 136 + kt * 32 + q * 8];
                f32x4 acc = {0.f, 0.f, 0.f, 0.f};
                #pragma unroll
                for (int kt = 0; kt < 4; ++kt) {
                    short8 bf = *(const short8*)&pack[w2off + ((size_t)(ct * 4 + kt) * 64 + l) * 8];
                    acc = __builtin_amdgcn_mfma_f32_16x16x32_bf16(a[kt], bf, acc, 0, 0, 0);
                }
                #pragma unroll
                for (int r = 0; r < 4; ++r) {
                    int gn = n0blk + nt * 16 + q * 4 + r;
                    if (gn < N)
                        z2cat[(size_t)gn * 128 + br * 64 + ct * 16 + m] = acc[r] + bias;
                }
            }
        }
    }
}

// ---------------- per-graph 9x9 gram from z2cat [N,128] (s=0..63,t=64..127)
__global__ __launch_bounds__(128) void einsum9_kernel(
    const float* __restrict__ z2cat, float* __restrict__ out, int G)
{
    int g = blockIdx.x;
    if (g >= G) return;
    __shared__ float ss[9][68];
    __shared__ float tt[9][68];
    const int tid = threadIdx.x;
    for (int idx = tid; idx < 9 * 64; idx += 128) {
        int n = idx >> 6, k = idx & 63;
        size_t row = (size_t)(g * 9 + n) * 128;
        ss[n][k] = z2cat[row + k];
        tt[n][k] = z2cat[row + 64 + k];
    }
    __syncthreads();
    if (tid < 81) {
        int i = tid / 9, j = tid - 9 * (tid / 9);
        float acc = 0.f;
        #pragma unroll
        for (int k = 0; k < 64; ++k) acc += ss[i][k] * tt[j][k];
        out[(size_t)g * 81 + i * 9 + j] = acc;
    }
}

extern "C" void kernel_launch(void* const* d_in, const int* in_sizes, int n_in,
                              void* d_out, int out_size, void* d_ws, size_t ws_size,
                              hipStream_t stream)
{
    const float* x  = (const float*)d_in[0];
    const int*   ei = (const int*)d_in[1];
    const int N_ = in_sizes[0] / 30;
    const int E_ = in_sizes[1] / 2;
    const int* src = ei;
    const int* dst = ei + E_;

    const float* w1s = (const float*)d_in[2];
    const float* b1s = (const float*)d_in[3];
    const float* w2s = (const float*)d_in[4];
    const float* b2s = (const float*)d_in[5];
    const float* w3s = (const float*)d_in[6];
    const float* b3s = (const float*)d_in[7];
    const float* w4s = (const float*)d_in[8];
    const float* b4s = (const float*)d_in[9];
    const float* w1t = (const float*)d_in[10];
    const float* b1t = (const float*)d_in[11];
    const float* w2t = (const float*)d_in[12];
    const float* b2t = (const float*)d_in[13];
    const float* w3t = (const float*)d_in[14];
    const float* b3t = (const float*)d_in[15];
    const float* w4t = (const float*)d_in[16];
    const float* b4t = (const float*)d_in[17];

    // ---- workspace layout ----
    int* deg    = (int*)d_ws;               // N
    int* rowptr = deg + N_;                 // N+1
    int* cursor = rowptr + N_ + 1;          // N
    int* bsum   = cursor + N_;              // 1024
    int* boff   = bsum + 1024;              // 1024
    int* col    = boff + 1024;              // E
    size_t int_bytes = ((size_t)3 * N_ + 1 + 2048 + (size_t)E_) * sizeof(int);
    size_t pb = (int_bytes + 15) & ~(size_t)15;
    unsigned short* packu = (unsigned short*)((char*)d_ws + pb);
    unsigned short* h1    = packu + PACK_USHORTS;         // [N,32] bf16
    unsigned short* z1cat = h1 + (size_t)N_ * 32;         // [N,256] bf16 s||t
    unsigned short* agg2  = z1cat + (size_t)N_ * 256;     // [N,256] bf16 incl self
    float* z2cat = (float*)(agg2 + (size_t)N_ * 256);     // [N,128] fp32 s||t
    size_t need = pb
                + ((size_t)PACK_USHORTS + (size_t)N_ * (32 + 256 + 256)) * 2
                + (size_t)N_ * 128 * 4;
    if (ws_size < need) return;

    const int nbE   = (E_ + 255) / 256;
    const int nb256 = (N_ + 255) / 256;
    const int nb64  = (N_ + 63) / 64;
    if (nb256 > 1024) return;   // single-block scan capacity

    // ---- weight packing (independent) ----
    wpack_kernel<<<176, 64, 0, stream>>>(w1s, w2s, w3s, w4s,
                                         w1t, w2t, w3t, w4t, packu);

    // ---- CSR build ----
    hipMemsetAsync(deg, 0, (size_t)N_ * sizeof(int), stream);
    hist_kernel<<<nbE, 256, 0, stream>>>(dst, deg, E_);
    blocksum_kernel<<<nb256, 256, 0, stream>>>(deg, bsum, N_);
    scanblock_kernel<<<1, 1024, 0, stream>>>(bsum, boff, nb256);
    rowptr_kernel<<<nb256, 256, 0, stream>>>(deg, boff, rowptr, cursor, N_, E_);
    scatter_kernel<<<nbE, 256, 0, stream>>>(src, dst, cursor, col, E_);

    // ---- layer-1 aggregation: high-TLP gather, fp32 sums -> bf16 h1 ----
    gather30_kernel<<<(N_ * 32 + 255) / 256, 256, 0, stream>>>(
        x, rowptr, col, h1, N_);

    // ---- layer 1: both branches (MFMA), writes bf16 z1cat ----
    mlp1_kernel<<<nb64, 256, 0, stream>>>(h1, packu,
        b1s, b2s, b1t, b2t, z1cat, N_);

    // ---- layer-2 aggregation: one 256-wide bf16 gather, self included ----
    gather256_kernel<<<(N_ * 64 + 255) / 256, 256, 0, stream>>>(
        z1cat, rowptr, col, agg2, N_);

    // ---- layer 2: both branches fused (MFMA) ----
    mlp2_kernel<<<nb64, 256, 0, stream>>>(agg2, packu,
        b3s, b4s, b3t, b4t, z2cat, N_);

    // ---- per-graph 9x9 gram ----
    einsum9_kernel<<<N_ / 9, 128, 0, stream>>>(z2cat, (float*)d_out, N_ / 9);
}

// Round 5
// 306.719 us; speedup vs baseline: 3.1662x; 1.0811x over previous
//
#include <hip/hip_runtime.h>
#include <hip/hip_bf16.h>

// GIN x2 layers x2 branches + per-graph 9x9 gram einsum.
// Round 5: MLP-optimized gathers. gather256 -> 32 lanes/node (uint4 16B/lane)
// with edge loop unrolled 4x/2x so 4 row loads are in flight per batch;
// gather30 unrolled the same way. Summation ORDER preserved exactly
// (adds sequential, only loads reordered) -> absmax must stay 14.5.
// All other kernels unchanged from round 4.

typedef __attribute__((ext_vector_type(8))) short short8;
typedef __attribute__((ext_vector_type(4))) float f32x4;

__device__ inline unsigned short f2bf(float f) {
    union { float f; unsigned u; } v; v.f = f;
    unsigned r = v.u + 0x7fffu + ((v.u >> 16) & 1u);   // RNE
    return (unsigned short)(r >> 16);
}
__device__ inline float bflo(unsigned u) { return __uint_as_float(u << 16); }
__device__ inline float bfhi(unsigned u) { return __uint_as_float(u & 0xffff0000u); }
__device__ inline unsigned packbf(float a, float b) {
    return (unsigned)f2bf(a) | ((unsigned)f2bf(b) << 16);
}

// pack offsets (ushort units): [w1s][w2s][w3s][w4s][w1t][w2t][w3t][w4t]
#define W1S_OFF 0
#define W2S_OFF 4096
#define W3S_OFF 20480
#define W4S_OFF 36864
#define W1T_OFF 45056
#define W2T_OFF 49152
#define W3T_OFF 65536
#define W4T_OFF 81920
#define PACK_USHORTS 90112

// ---------------------------------------------------------------- CSR build
__global__ __launch_bounds__(256) void hist_kernel(
    const int* __restrict__ dst, int* __restrict__ deg, int E)
{
    int e = blockIdx.x * 256 + threadIdx.x;
    if (e < E) atomicAdd(&deg[dst[e]], 1);
}

__global__ __launch_bounds__(256) void blocksum_kernel(
    const int* __restrict__ deg, int* __restrict__ bsum, int N)
{
    __shared__ int sh[256];
    int i = blockIdx.x * 256 + threadIdx.x;
    sh[threadIdx.x] = (i < N) ? deg[i] : 0;
    __syncthreads();
    for (int off = 128; off > 0; off >>= 1) {
        if (threadIdx.x < off) sh[threadIdx.x] += sh[threadIdx.x + off];
        __syncthreads();
    }
    if (threadIdx.x == 0) bsum[blockIdx.x] = sh[0];
}

__global__ __launch_bounds__(1024) void scanblock_kernel(
    const int* __restrict__ bsum, int* __restrict__ boff, int nb)
{
    __shared__ int sh[1024];
    int t = threadIdx.x;
    int v = (t < nb) ? bsum[t] : 0;
    sh[t] = v;
    __syncthreads();
    for (int off = 1; off < 1024; off <<= 1) {
        int a = (t >= off) ? sh[t - off] : 0;
        __syncthreads();
        sh[t] += a;
        __syncthreads();
    }
    if (t < nb) boff[t] = sh[t] - v;   // exclusive
}

__global__ __launch_bounds__(256) void rowptr_kernel(
    const int* __restrict__ deg, const int* __restrict__ boff,
    int* __restrict__ rowptr, int* __restrict__ cursor, int N, int E)
{
    __shared__ int sh[256];
    int t = threadIdx.x;
    int i = blockIdx.x * 256 + t;
    int v = (i < N) ? deg[i] : 0;
    sh[t] = v;
    __syncthreads();
    for (int off = 1; off < 256; off <<= 1) {
        int a = (t >= off) ? sh[t - off] : 0;
        __syncthreads();
        sh[t] += a;
        __syncthreads();
    }
    if (i < N) {
        int r = boff[blockIdx.x] + sh[t] - v;
        rowptr[i] = r;
        cursor[i] = r;
    }
    if (i == 0) rowptr[N] = E;
}

__global__ __launch_bounds__(256) void scatter_kernel(
    const int* __restrict__ src, const int* __restrict__ dst,
    int* __restrict__ cursor, int* __restrict__ col, int E)
{
    int e = blockIdx.x * 256 + threadIdx.x;
    if (e < E) {
        int d = dst[e];
        int pos = atomicAdd(&cursor[d], 1);
        col[pos] = src[e];
    }
}

// ------------------------------------------------------------ weight packer
// B-frag order for 16x16x32 bf16 (m89/m91-verified): lane l holds
// B[k = kt*32 + (l>>4)*8 + j][n = ct*16 + (l&15)], j=0..7 contiguous.
__global__ __launch_bounds__(64) void wpack_kernel(
    const float* w0, const float* w1, const float* w2, const float* w3,
    const float* w4, const float* w5, const float* w6, const float* w7,
    unsigned short* __restrict__ pack)
{
    const int prefix[9] = {0, 8, 40, 72, 88, 96, 128, 160, 176};
    const int KTa[8] = {1, 4, 4, 4, 1, 4, 4, 4};
    const int KRa[8] = {30, 128, 128, 128, 30, 128, 128, 128};
    const int Ca[8]  = {128, 128, 128, 64, 128, 128, 128, 64};
    const int DOFF[8] = {W1S_OFF, W2S_OFF, W3S_OFF, W4S_OFF,
                         W1T_OFF, W2T_OFF, W3T_OFF, W4T_OFF};
    const float* Ws[8] = {w0, w1, w2, w3, w4, w5, w6, w7};
    int bid = blockIdx.x;
    int mi = 0;
    while (mi < 7 && bid >= prefix[mi + 1]) ++mi;
    int lt = bid - prefix[mi];
    int kt = lt % KTa[mi], ct = lt / KTa[mi];
    const float* W = Ws[mi];
    int l = threadIdx.x;
    int n = ct * 16 + (l & 15);
    for (int j = 0; j < 8; ++j) {
        int k = kt * 32 + (l >> 4) * 8 + j;
        float v = (k < KRa[mi]) ? W[(size_t)k * Ca[mi] + n] : 0.f;
        pack[(size_t)DOFF[mi] + (size_t)lt * 512 + l * 8 + j] = f2bf(v);
    }
}

// ------------------------------------------- layer-1 aggregation (gather)
// One 32-lane group per node: h1[n] = bf16(x[n] + sum_{s->n} x[s]).
// Edge loop unrolled 4x/2x: col loads then row loads issue independently;
// adds stay strictly sequential (bit-identical to the rolled loop).
__global__ __launch_bounds__(256) void gather30_kernel(
    const float* __restrict__ x, const int* __restrict__ rowptr,
    const int* __restrict__ col, unsigned short* __restrict__ h1, int N)
{
    int gid = blockIdx.x * 256 + threadIdx.x;
    int node = gid >> 5;
    if (node >= N) return;
    int ln = gid & 31;
    bool act = (ln < 30);
    float acc = act ? x[(size_t)node * 30 + ln] : 0.f;
    int b = rowptr[node], e = rowptr[node + 1];
    int i = b;
    for (; i + 4 <= e; i += 4) {
        int s0 = col[i], s1 = col[i + 1], s2 = col[i + 2], s3 = col[i + 3];
        float v0 = act ? x[(size_t)s0 * 30 + ln] : 0.f;
        float v1 = act ? x[(size_t)s1 * 30 + ln] : 0.f;
        float v2 = act ? x[(size_t)s2 * 30 + ln] : 0.f;
        float v3 = act ? x[(size_t)s3 * 30 + ln] : 0.f;
        acc += v0; acc += v1; acc += v2; acc += v3;
    }
    for (; i + 2 <= e; i += 2) {
        int s0 = col[i], s1 = col[i + 1];
        float v0 = act ? x[(size_t)s0 * 30 + ln] : 0.f;
        float v1 = act ? x[(size_t)s1 * 30 + ln] : 0.f;
        acc += v0; acc += v1;
    }
    for (; i < e; ++i) {
        int s0 = col[i];
        if (act) acc += x[(size_t)s0 * 30 + ln];
    }
    h1[(size_t)node * 32 + ln] = act ? f2bf(acc) : (unsigned short)0;
}

// ------------------------------------------------- layer-1 MLP (dual branch)
__global__ __launch_bounds__(256) void mlp1_kernel(
    const unsigned short* __restrict__ h1, const unsigned short* __restrict__ pack,
    const float* __restrict__ b1s, const float* __restrict__ b2s,
    const float* __restrict__ b1t, const float* __restrict__ b2t,
    unsigned short* __restrict__ z1cat, int N)
{
    __shared__ __align__(16) unsigned short hs[64 * 40];
    __shared__ __align__(16) unsigned short hm[64 * 136];
    const int tid = threadIdx.x;
    const int n0blk = blockIdx.x * 64;

    // ---- stage h1 rows (32 bf16 each), coalesced 16B/thread ----
    {
        int row = tid >> 2, off = tid & 3;
        int gn = n0blk + row;
        short8 v = {0, 0, 0, 0, 0, 0, 0, 0};
        if (gn < N) v = *(const short8*)&h1[(size_t)gn * 32 + off * 8];
        *(short8*)&hs[row * 40 + off * 8] = v;
    }
    __syncthreads();

    const int wv = tid >> 6, l = tid & 63, q = l >> 4, m = l & 15;

    for (int br = 0; br < 2; ++br) {
        const float* B1 = br ? b1t : b1s;
        const float* B2 = br ? b2t : b2s;
        const int w1off = br ? W1T_OFF : W1S_OFF;
        const int w2off = br ? W2T_OFF : W2S_OFF;

        // ---- stage 1: hm = relu(h1 @ W1 + b1), K=32 single MFMA ----
        {
            short8 a[4];
            #pragma unroll
            for (int nt = 0; nt < 4; ++nt)
                a[nt] = *(const short8*)&hs[(nt * 16 + m) * 40 + q * 8];
            #pragma unroll
            for (int ci = 0; ci < 2; ++ci) {
                int ct = wv * 2 + ci;
                short8 bf = *(const short8*)&pack[w1off + ((size_t)ct * 64 + l) * 8];
                float bias = B1[ct * 16 + m];
                #pragma unroll
                for (int nt = 0; nt < 4; ++nt) {
                    f32x4 acc = {0.f, 0.f, 0.f, 0.f};
                    acc = __builtin_amdgcn_mfma_f32_16x16x32_bf16(a[nt], bf, acc, 0, 0, 0);
                    #pragma unroll
                    for (int r = 0; r < 4; ++r) {
                        float v = fmaxf(acc[r] + bias, 0.f);
                        hm[(nt * 16 + q * 4 + r) * 136 + ct * 16 + m] = f2bf(v);
                    }
                }
            }
        }
        __syncthreads();

        // ---- stage 2: z1 = hm @ W2 + b2 (K=128), defer writeback ----
        f32x4 acc2[4][2];
        #pragma unroll
        for (int nt = 0; nt < 4; ++nt)
            #pragma unroll
            for (int ci = 0; ci < 2; ++ci)
                acc2[nt][ci] = (f32x4){0.f, 0.f, 0.f, 0.f};
        for (int nt = 0; nt < 4; ++nt) {
            short8 a[4];
            #pragma unroll
            for (int kt = 0; kt < 4; ++kt)
                a[kt] = *(const short8*)&hm[(nt * 16 + m) * 136 + kt * 32 + q * 8];
            #pragma unroll
            for (int ci = 0; ci < 2; ++ci) {
                int ct = wv * 2 + ci;
                #pragma unroll
                for (int kt = 0; kt < 4; ++kt) {
                    short8 bf = *(const short8*)&pack[w2off + ((size_t)(ct * 4 + kt) * 64 + l) * 8];
                    acc2[nt][ci] = __builtin_amdgcn_mfma_f32_16x16x32_bf16(a[kt], bf, acc2[nt][ci], 0, 0, 0);
                }
            }
        }
        __syncthreads();   // all hm A-frag reads complete
        #pragma unroll
        for (int ci = 0; ci < 2; ++ci) {
            int ct = wv * 2 + ci;
            float bias = B2[ct * 16 + m];
            #pragma unroll
            for (int nt = 0; nt < 4; ++nt)
                #pragma unroll
                for (int r = 0; r < 4; ++r)
                    hm[(nt * 16 + q * 4 + r) * 136 + ct * 16 + m] =
                        f2bf(acc2[nt][ci][r] + bias);
        }
        __syncthreads();
        // coalesced copy-out: 64 rows x 128 bf16
        for (int c = tid; c < 1024; c += 256) {
            int row = c >> 4, off = c & 15;
            int gn = n0blk + row;
            if (gn < N) {
                short8 v = *(const short8*)&hm[row * 136 + off * 8];
                *(short8*)&z1cat[(size_t)gn * 256 + br * 128 + off * 8] = v;
            }
        }
        __syncthreads();   // before branch t rewrites hm
    }
}

// --------------------------------------------- layer-2 aggregation (gather)
// 32 lanes per node, uint4 (16B) per lane. Edge loop unrolled 4x/2x so the
// 512B row loads issue independently; adds strictly sequential (bit-identical
// summation order vs the rolled loop). fp32 sums, bf16 out.
__global__ __launch_bounds__(256) void gather256_kernel(
    const unsigned short* __restrict__ z1, const int* __restrict__ rowptr,
    const int* __restrict__ col, unsigned short* __restrict__ agg2, int N)
{
    int gid = blockIdx.x * 256 + threadIdx.x;
    int w = gid >> 5;
    if (w >= N) return;
    int l = gid & 31;
    const uint4* base = (const uint4*)z1;        // 32 uint4 per row
    uint4 s = base[(size_t)w * 32 + l];          // self
    float a0 = bflo(s.x), a1 = bfhi(s.x), a2 = bflo(s.y), a3 = bfhi(s.y);
    float a4 = bflo(s.z), a5 = bfhi(s.z), a6 = bflo(s.w), a7 = bfhi(s.w);
    int b = rowptr[w], e = rowptr[w + 1];
    int i = b;
    for (; i + 4 <= e; i += 4) {
        int s0 = col[i], s1 = col[i + 1], s2 = col[i + 2], s3 = col[i + 3];
        uint4 v0 = base[(size_t)s0 * 32 + l];
        uint4 v1 = base[(size_t)s1 * 32 + l];
        uint4 v2 = base[(size_t)s2 * 32 + l];
        uint4 v3 = base[(size_t)s3 * 32 + l];
        a0 += bflo(v0.x); a1 += bfhi(v0.x); a2 += bflo(v0.y); a3 += bfhi(v0.y);
        a4 += bflo(v0.z); a5 += bfhi(v0.z); a6 += bflo(v0.w); a7 += bfhi(v0.w);
        a0 += bflo(v1.x); a1 += bfhi(v1.x); a2 += bflo(v1.y); a3 += bfhi(v1.y);
        a4 += bflo(v1.z); a5 += bfhi(v1.z); a6 += bflo(v1.w); a7 += bfhi(v1.w);
        a0 += bflo(v2.x); a1 += bfhi(v2.x); a2 += bflo(v2.y); a3 += bfhi(v2.y);
        a4 += bflo(v2.z); a5 += bfhi(v2.z); a6 += bflo(v2.w); a7 += bfhi(v2.w);
        a0 += bflo(v3.x); a1 += bfhi(v3.x); a2 += bflo(v3.y); a3 += bfhi(v3.y);
        a4 += bflo(v3.z); a5 += bfhi(v3.z); a6 += bflo(v3.w); a7 += bfhi(v3.w);
    }
    for (; i + 2 <= e; i += 2) {
        int s0 = col[i], s1 = col[i + 1];
        uint4 v0 = base[(size_t)s0 * 32 + l];
        uint4 v1 = base[(size_t)s1 * 32 + l];
        a0 += bflo(v0.x); a1 += bfhi(v0.x); a2 += bflo(v0.y); a3 += bfhi(v0.y);
        a4 += bflo(v0.z); a5 += bfhi(v0.z); a6 += bflo(v0.w); a7 += bfhi(v0.w);
        a0 += bflo(v1.x); a1 += bfhi(v1.x); a2 += bflo(v1.y); a3 += bfhi(v1.y);
        a4 += bflo(v1.z); a5 += bfhi(v1.z); a6 += bflo(v1.w); a7 += bfhi(v1.w);
    }
    for (; i < e; ++i) {
        uint4 v0 = base[(size_t)col[i] * 32 + l];
        a0 += bflo(v0.x); a1 += bfhi(v0.x); a2 += bflo(v0.y); a3 += bfhi(v0.y);
        a4 += bflo(v0.z); a5 += bfhi(v0.z); a6 += bflo(v0.w); a7 += bfhi(v0.w);
    }
    uint4 o;
    o.x = packbf(a0, a1); o.y = packbf(a2, a3);
    o.z = packbf(a4, a5); o.w = packbf(a6, a7);
    ((uint4*)agg2)[(size_t)w * 32 + l] = o;
}

// --------------------------------------- layer-2 MLP (both branches fused)
__global__ __launch_bounds__(256) void mlp2_kernel(
    const unsigned short* __restrict__ agg2,
    const unsigned short* __restrict__ pack,
    const float* __restrict__ b3s, const float* __restrict__ b4s,
    const float* __restrict__ b3t, const float* __restrict__ b4t,
    float* __restrict__ z2cat, int N)
{
    __shared__ __align__(16) unsigned short hs[64 * 264];
    __shared__ __align__(16) unsigned short hm[64 * 136];
    const int tid = threadIdx.x;
    const int n0blk = blockIdx.x * 64;

    // ---- stage full rows: 64 x 256 bf16, 16B/thread x 8 ----
    for (int c = tid; c < 2048; c += 256) {
        int row = c >> 5, off = c & 31;
        int gn = n0blk + row;
        short8 v = {0, 0, 0, 0, 0, 0, 0, 0};
        if (gn < N) v = *(const short8*)&agg2[(size_t)gn * 256 + off * 8];
        *(short8*)&hs[row * 264 + off * 8] = v;
    }
    __syncthreads();

    const int wv = tid >> 6, l = tid & 63, q = l >> 4, m = l & 15;

    for (int br = 0; br < 2; ++br) {
        const int w1off = br ? W3T_OFF : W3S_OFF;
        const int w2off = br ? W4T_OFF : W4S_OFF;
        const float* B1 = br ? b3t : b3s;
        const float* B2 = br ? b4t : b4s;
        if (br) __syncthreads();   // br0 stage2 hm reads done before rewrite

        // ---- stage 1: hm = relu(hs[:, br*128..] @ W3 + b3), K=128 ----
        for (int nt = 0; nt < 4; ++nt) {
            short8 a[4];
            #pragma unroll
            for (int kt = 0; kt < 4; ++kt)
                a[kt] = *(const short8*)&hs[(nt * 16 + m) * 264 + br * 128 + kt * 32 + q * 8];
            #pragma unroll
            for (int ci = 0; ci < 2; ++ci) {
                int ct = wv * 2 + ci;
                f32x4 acc = {0.f, 0.f, 0.f, 0.f};
                #pragma unroll
                for (int kt = 0; kt < 4; ++kt) {
                    short8 bf = *(const short8*)&pack[w1off + ((size_t)(ct * 4 + kt) * 64 + l) * 8];
                    acc = __builtin_amdgcn_mfma_f32_16x16x32_bf16(a[kt], bf, acc, 0, 0, 0);
                }
                float bias = B1[ct * 16 + m];
                #pragma unroll
                for (int r = 0; r < 4; ++r) {
                    float v = fmaxf(acc[r] + bias, 0.f);
                    hm[(nt * 16 + q * 4 + r) * 136 + ct * 16 + m] = f2bf(v);
                }
            }
        }
        __syncthreads();

        // ---- stage 2: z2cat slice = hm @ W4 + b4 (64 cols, 1 ct/wave) ----
        {
            int ct = wv;
            float bias = B2[ct * 16 + m];
            for (int nt = 0; nt < 4; ++nt) {
                short8 a[4];
                #pragma unroll
                for (int kt = 0; kt < 4; ++kt)
                    a[kt] = *(const short8*)&hm[(nt * 16 + m) * 136 + kt * 32 + q * 8];
                f32x4 acc = {0.f, 0.f, 0.f, 0.f};
                #pragma unroll
                for (int kt = 0; kt < 4; ++kt) {
                    short8 bf = *(const short8*)&pack[w2off + ((size_t)(ct * 4 + kt) * 64 + l) * 8];
                    acc = __builtin_amdgcn_mfma_f32_16x16x32_bf16(a[kt], bf, acc, 0, 0, 0);
                }
                #pragma unroll
                for (int r = 0; r < 4; ++r) {
                    int gn = n0blk + nt * 16 + q * 4 + r;
                    if (gn < N)
                        z2cat[(size_t)gn * 128 + br * 64 + ct * 16 + m] = acc[r] + bias;
                }
            }
        }
    }
}

// ---------------- per-graph 9x9 gram from z2cat [N,128] (s=0..63,t=64..127)
__global__ __launch_bounds__(128) void einsum9_kernel(
    const float* __restrict__ z2cat, float* __restrict__ out, int G)
{
    int g = blockIdx.x;
    if (g >= G) return;
    __shared__ float ss[9][68];
    __shared__ float tt[9][68];
    const int tid = threadIdx.x;
    for (int idx = tid; idx < 9 * 64; idx += 128) {
        int n = idx >> 6, k = idx & 63;
        size_t row = (size_t)(g * 9 + n) * 128;
        ss[n][k] = z2cat[row + k];
        tt[n][k] = z2cat[row + 64 + k];
    }
    __syncthreads();
    if (tid < 81) {
        int i = tid / 9, j = tid - 9 * (tid / 9);
        float acc = 0.f;
        #pragma unroll
        for (int k = 0; k < 64; ++k) acc += ss[i][k] * tt[j][k];
        out[(size_t)g * 81 + i * 9 + j] = acc;
    }
}

extern "C" void kernel_launch(void* const* d_in, const int* in_sizes, int n_in,
                              void* d_out, int out_size, void* d_ws, size_t ws_size,
                              hipStream_t stream)
{
    const float* x  = (const float*)d_in[0];
    const int*   ei = (const int*)d_in[1];
    const int N_ = in_sizes[0] / 30;
    const int E_ = in_sizes[1] / 2;
    const int* src = ei;
    const int* dst = ei + E_;

    const float* w1s = (const float*)d_in[2];
    const float* b1s = (const float*)d_in[3];
    const float* w2s = (const float*)d_in[4];
    const float* b2s = (const float*)d_in[5];
    const float* w3s = (const float*)d_in[6];
    const float* b3s = (const float*)d_in[7];
    const float* w4s = (const float*)d_in[8];
    const float* b4s = (const float*)d_in[9];
    const float* w1t = (const float*)d_in[10];
    const float* b1t = (const float*)d_in[11];
    const float* w2t = (const float*)d_in[12];
    const float* b2t = (const float*)d_in[13];
    const float* w3t = (const float*)d_in[14];
    const float* b3t = (const float*)d_in[15];
    const float* w4t = (const float*)d_in[16];
    const float* b4t = (const float*)d_in[17];

    // ---- workspace layout ----
    int* deg    = (int*)d_ws;               // N
    int* rowptr = deg + N_;                 // N+1
    int* cursor = rowptr + N_ + 1;          // N
    int* bsum   = cursor + N_;              // 1024
    int* boff   = bsum + 1024;              // 1024
    int* col    = boff + 1024;              // E
    size_t int_bytes = ((size_t)3 * N_ + 1 + 2048 + (size_t)E_) * sizeof(int);
    size_t pb = (int_bytes + 15) & ~(size_t)15;
    unsigned short* packu = (unsigned short*)((char*)d_ws + pb);
    unsigned short* h1    = packu + PACK_USHORTS;         // [N,32] bf16
    unsigned short* z1cat = h1 + (size_t)N_ * 32;         // [N,256] bf16 s||t
    unsigned short* agg2  = z1cat + (size_t)N_ * 256;     // [N,256] bf16 incl self
    float* z2cat = (float*)(agg2 + (size_t)N_ * 256);     // [N,128] fp32 s||t
    size_t need = pb
                + ((size_t)PACK_USHORTS + (size_t)N_ * (32 + 256 + 256)) * 2
                + (size_t)N_ * 128 * 4;
    if (ws_size < need) return;

    const int nbE   = (E_ + 255) / 256;
    const int nb256 = (N_ + 255) / 256;
    const int nb64  = (N_ + 63) / 64;
    if (nb256 > 1024) return;   // single-block scan capacity

    // ---- weight packing (independent) ----
    wpack_kernel<<<176, 64, 0, stream>>>(w1s, w2s, w3s, w4s,
                                         w1t, w2t, w3t, w4t, packu);

    // ---- CSR build ----
    hipMemsetAsync(deg, 0, (size_t)N_ * sizeof(int), stream);
    hist_kernel<<<nbE, 256, 0, stream>>>(dst, deg, E_);
    blocksum_kernel<<<nb256, 256, 0, stream>>>(deg, bsum, N_);
    scanblock_kernel<<<1, 1024, 0, stream>>>(bsum, boff, nb256);
    rowptr_kernel<<<nb256, 256, 0, stream>>>(deg, boff, rowptr, cursor, N_, E_);
    scatter_kernel<<<nbE, 256, 0, stream>>>(src, dst, cursor, col, E_);

    // ---- layer-1 aggregation: high-TLP gather, fp32 sums -> bf16 h1 ----
    gather30_kernel<<<(N_ * 32 + 255) / 256, 256, 0, stream>>>(
        x, rowptr, col, h1, N_);

    // ---- layer 1: both branches (MFMA), writes bf16 z1cat ----
    mlp1_kernel<<<nb64, 256, 0, stream>>>(h1, packu,
        b1s, b2s, b1t, b2t, z1cat, N_);

    // ---- layer-2 aggregation: one 256-wide bf16 gather, self included ----
    gather256_kernel<<<(N_ * 32 + 255) / 256, 256, 0, stream>>>(
        z1cat, rowptr, col, agg2, N_);

    // ---- layer 2: both branches fused (MFMA) ----
    mlp2_kernel<<<nb64, 256, 0, stream>>>(agg2, packu,
        b3s, b4s, b3t, b4t, z2cat, N_);

    // ---- per-graph 9x9 gram ----
    einsum9_kernel<<<N_ / 9, 128, 0, stream>>>(z2cat, (float*)d_out, N_ / 9);
}

// Round 6
// 293.036 us; speedup vs baseline: 3.3140x; 1.0467x over previous
//
#include <hip/hip_runtime.h>
#include <hip/hip_bf16.h>

// GIN x2 layers x2 branches + per-graph 9x9 gram einsum.
// Round 6: gather256 fused into mlp2's LDS staging (agg2 buffer deleted,
// -92 MB traffic, -1 dispatch); gather30 -> 8 lanes/node float4 on a padded
// fp32 xpad[N,32] (bit-identical per-feature add order). All rounding points
// unchanged -> absmax must stay exactly 14.5.

typedef __attribute__((ext_vector_type(8))) short short8;
typedef __attribute__((ext_vector_type(4))) float f32x4;

__device__ inline unsigned short f2bf(float f) {
    union { float f; unsigned u; } v; v.f = f;
    unsigned r = v.u + 0x7fffu + ((v.u >> 16) & 1u);   // RNE
    return (unsigned short)(r >> 16);
}
__device__ inline float bflo(unsigned u) { return __uint_as_float(u << 16); }
__device__ inline float bfhi(unsigned u) { return __uint_as_float(u & 0xffff0000u); }
__device__ inline unsigned packbf(float a, float b) {
    return (unsigned)f2bf(a) | ((unsigned)f2bf(b) << 16);
}

// pack offsets (ushort units): [w1s][w2s][w3s][w4s][w1t][w2t][w3t][w4t]
#define W1S_OFF 0
#define W2S_OFF 4096
#define W3S_OFF 20480
#define W4S_OFF 36864
#define W1T_OFF 45056
#define W2T_OFF 49152
#define W3T_OFF 65536
#define W4T_OFF 81920
#define PACK_USHORTS 90112

// ---------------------------------------------------------------- CSR build
__global__ __launch_bounds__(256) void hist_kernel(
    const int* __restrict__ dst, int* __restrict__ deg, int E)
{
    int e = blockIdx.x * 256 + threadIdx.x;
    if (e < E) atomicAdd(&deg[dst[e]], 1);
}

__global__ __launch_bounds__(256) void blocksum_kernel(
    const int* __restrict__ deg, int* __restrict__ bsum, int N)
{
    __shared__ int sh[256];
    int i = blockIdx.x * 256 + threadIdx.x;
    sh[threadIdx.x] = (i < N) ? deg[i] : 0;
    __syncthreads();
    for (int off = 128; off > 0; off >>= 1) {
        if (threadIdx.x < off) sh[threadIdx.x] += sh[threadIdx.x + off];
        __syncthreads();
    }
    if (threadIdx.x == 0) bsum[blockIdx.x] = sh[0];
}

__global__ __launch_bounds__(1024) void scanblock_kernel(
    const int* __restrict__ bsum, int* __restrict__ boff, int nb)
{
    __shared__ int sh[1024];
    int t = threadIdx.x;
    int v = (t < nb) ? bsum[t] : 0;
    sh[t] = v;
    __syncthreads();
    for (int off = 1; off < 1024; off <<= 1) {
        int a = (t >= off) ? sh[t - off] : 0;
        __syncthreads();
        sh[t] += a;
        __syncthreads();
    }
    if (t < nb) boff[t] = sh[t] - v;   // exclusive
}

__global__ __launch_bounds__(256) void rowptr_kernel(
    const int* __restrict__ deg, const int* __restrict__ boff,
    int* __restrict__ rowptr, int* __restrict__ cursor, int N, int E)
{
    __shared__ int sh[256];
    int t = threadIdx.x;
    int i = blockIdx.x * 256 + t;
    int v = (i < N) ? deg[i] : 0;
    sh[t] = v;
    __syncthreads();
    for (int off = 1; off < 256; off <<= 1) {
        int a = (t >= off) ? sh[t - off] : 0;
        __syncthreads();
        sh[t] += a;
        __syncthreads();
    }
    if (i < N) {
        int r = boff[blockIdx.x] + sh[t] - v;
        rowptr[i] = r;
        cursor[i] = r;
    }
    if (i == 0) rowptr[N] = E;
}

__global__ __launch_bounds__(256) void scatter_kernel(
    const int* __restrict__ src, const int* __restrict__ dst,
    int* __restrict__ cursor, int* __restrict__ col, int E)
{
    int e = blockIdx.x * 256 + threadIdx.x;
    if (e < E) {
        int d = dst[e];
        int pos = atomicAdd(&cursor[d], 1);
        col[pos] = src[e];
    }
}

// ------------------------------------------------------------ weight packer
// B-frag order for 16x16x32 bf16 (m89/m91-verified): lane l holds
// B[k = kt*32 + (l>>4)*8 + j][n = ct*16 + (l&15)], j=0..7 contiguous.
__global__ __launch_bounds__(64) void wpack_kernel(
    const float* w0, const float* w1, const float* w2, const float* w3,
    const float* w4, const float* w5, const float* w6, const float* w7,
    unsigned short* __restrict__ pack)
{
    const int prefix[9] = {0, 8, 40, 72, 88, 96, 128, 160, 176};
    const int KTa[8] = {1, 4, 4, 4, 1, 4, 4, 4};
    const int KRa[8] = {30, 128, 128, 128, 30, 128, 128, 128};
    const int Ca[8]  = {128, 128, 128, 64, 128, 128, 128, 64};
    const int DOFF[8] = {W1S_OFF, W2S_OFF, W3S_OFF, W4S_OFF,
                         W1T_OFF, W2T_OFF, W3T_OFF, W4T_OFF};
    const float* Ws[8] = {w0, w1, w2, w3, w4, w5, w6, w7};
    int bid = blockIdx.x;
    int mi = 0;
    while (mi < 7 && bid >= prefix[mi + 1]) ++mi;
    int lt = bid - prefix[mi];
    int kt = lt % KTa[mi], ct = lt / KTa[mi];
    const float* W = Ws[mi];
    int l = threadIdx.x;
    int n = ct * 16 + (l & 15);
    for (int j = 0; j < 8; ++j) {
        int k = kt * 32 + (l >> 4) * 8 + j;
        float v = (k < KRa[mi]) ? W[(size_t)k * Ca[mi] + n] : 0.f;
        pack[(size_t)DOFF[mi] + (size_t)lt * 512 + l * 8 + j] = f2bf(v);
    }
}

// ---------------------------------------------------- x padding (fp32 exact)
__global__ __launch_bounds__(256) void xpad_kernel(
    const float* __restrict__ x, float* __restrict__ xpad, int N)
{
    int gid = blockIdx.x * 256 + threadIdx.x;
    if (gid >= N * 32) return;
    int n = gid >> 5, f = gid & 31;
    xpad[gid] = (f < 30) ? x[(size_t)n * 30 + f] : 0.f;
}

// ------------------------------------------- layer-1 aggregation (gather)
// 8 lanes/node, float4 (16B) per lane over xpad[N,32] fp32. Per-feature
// sequential add order identical to prior rounds -> bit-identical h1.
__global__ __launch_bounds__(256) void gather30_kernel(
    const float* __restrict__ xpad, const int* __restrict__ rowptr,
    const int* __restrict__ col, unsigned short* __restrict__ h1, int N)
{
    int gid = blockIdx.x * 256 + threadIdx.x;
    int node = gid >> 3;
    if (node >= N) return;
    int l = gid & 7;
    const float4* base = (const float4*)xpad;   // 8 float4 per row
    float4 a = base[(size_t)node * 8 + l];      // self (exact fp32)
    int b = rowptr[node], e = rowptr[node + 1];
    int i = b;
    for (; i + 4 <= e; i += 4) {
        int s0 = col[i], s1 = col[i + 1], s2 = col[i + 2], s3 = col[i + 3];
        float4 v0 = base[(size_t)s0 * 8 + l];
        float4 v1 = base[(size_t)s1 * 8 + l];
        float4 v2 = base[(size_t)s2 * 8 + l];
        float4 v3 = base[(size_t)s3 * 8 + l];
        a.x += v0.x; a.y += v0.y; a.z += v0.z; a.w += v0.w;
        a.x += v1.x; a.y += v1.y; a.z += v1.z; a.w += v1.w;
        a.x += v2.x; a.y += v2.y; a.z += v2.z; a.w += v2.w;
        a.x += v3.x; a.y += v3.y; a.z += v3.z; a.w += v3.w;
    }
    for (; i + 2 <= e; i += 2) {
        int s0 = col[i], s1 = col[i + 1];
        float4 v0 = base[(size_t)s0 * 8 + l];
        float4 v1 = base[(size_t)s1 * 8 + l];
        a.x += v0.x; a.y += v0.y; a.z += v0.z; a.w += v0.w;
        a.x += v1.x; a.y += v1.y; a.z += v1.z; a.w += v1.w;
    }
    for (; i < e; ++i) {
        float4 v0 = base[(size_t)col[i] * 8 + l];
        a.x += v0.x; a.y += v0.y; a.z += v0.z; a.w += v0.w;
    }
    uint2 o; o.x = packbf(a.x, a.y); o.y = packbf(a.z, a.w);
    ((uint2*)h1)[(size_t)node * 8 + l] = o;
}

// ------------------------------------------------- layer-1 MLP (dual branch)
__global__ __launch_bounds__(256) void mlp1_kernel(
    const unsigned short* __restrict__ h1, const unsigned short* __restrict__ pack,
    const float* __restrict__ b1s, const float* __restrict__ b2s,
    const float* __restrict__ b1t, const float* __restrict__ b2t,
    unsigned short* __restrict__ z1cat, int N)
{
    __shared__ __align__(16) unsigned short hs[64 * 40];
    __shared__ __align__(16) unsigned short hm[64 * 136];
    const int tid = threadIdx.x;
    const int n0blk = blockIdx.x * 64;

    // ---- stage h1 rows (32 bf16 each), coalesced 16B/thread ----
    {
        int row = tid >> 2, off = tid & 3;
        int gn = n0blk + row;
        short8 v = {0, 0, 0, 0, 0, 0, 0, 0};
        if (gn < N) v = *(const short8*)&h1[(size_t)gn * 32 + off * 8];
        *(short8*)&hs[row * 40 + off * 8] = v;
    }
    __syncthreads();

    const int wv = tid >> 6, l = tid & 63, q = l >> 4, m = l & 15;

    for (int br = 0; br < 2; ++br) {
        const float* B1 = br ? b1t : b1s;
        const float* B2 = br ? b2t : b2s;
        const int w1off = br ? W1T_OFF : W1S_OFF;
        const int w2off = br ? W2T_OFF : W2S_OFF;

        // ---- stage 1: hm = relu(h1 @ W1 + b1), K=32 single MFMA ----
        {
            short8 a[4];
            #pragma unroll
            for (int nt = 0; nt < 4; ++nt)
                a[nt] = *(const short8*)&hs[(nt * 16 + m) * 40 + q * 8];
            #pragma unroll
            for (int ci = 0; ci < 2; ++ci) {
                int ct = wv * 2 + ci;
                short8 bf = *(const short8*)&pack[w1off + ((size_t)ct * 64 + l) * 8];
                float bias = B1[ct * 16 + m];
                #pragma unroll
                for (int nt = 0; nt < 4; ++nt) {
                    f32x4 acc = {0.f, 0.f, 0.f, 0.f};
                    acc = __builtin_amdgcn_mfma_f32_16x16x32_bf16(a[nt], bf, acc, 0, 0, 0);
                    #pragma unroll
                    for (int r = 0; r < 4; ++r) {
                        float v = fmaxf(acc[r] + bias, 0.f);
                        hm[(nt * 16 + q * 4 + r) * 136 + ct * 16 + m] = f2bf(v);
                    }
                }
            }
        }
        __syncthreads();

        // ---- stage 2: z1 = hm @ W2 + b2 (K=128), defer writeback ----
        f32x4 acc2[4][2];
        #pragma unroll
        for (int nt = 0; nt < 4; ++nt)
            #pragma unroll
            for (int ci = 0; ci < 2; ++ci)
                acc2[nt][ci] = (f32x4){0.f, 0.f, 0.f, 0.f};
        for (int nt = 0; nt < 4; ++nt) {
            short8 a[4];
            #pragma unroll
            for (int kt = 0; kt < 4; ++kt)
                a[kt] = *(const short8*)&hm[(nt * 16 + m) * 136 + kt * 32 + q * 8];
            #pragma unroll
            for (int ci = 0; ci < 2; ++ci) {
                int ct = wv * 2 + ci;
                #pragma unroll
                for (int kt = 0; kt < 4; ++kt) {
                    short8 bf = *(const short8*)&pack[w2off + ((size_t)(ct * 4 + kt) * 64 + l) * 8];
                    acc2[nt][ci] = __builtin_amdgcn_mfma_f32_16x16x32_bf16(a[kt], bf, acc2[nt][ci], 0, 0, 0);
                }
            }
        }
        __syncthreads();   // all hm A-frag reads complete
        #pragma unroll
        for (int ci = 0; ci < 2; ++ci) {
            int ct = wv * 2 + ci;
            float bias = B2[ct * 16 + m];
            #pragma unroll
            for (int nt = 0; nt < 4; ++nt)
                #pragma unroll
                for (int r = 0; r < 4; ++r)
                    hm[(nt * 16 + q * 4 + r) * 136 + ct * 16 + m] =
                        f2bf(acc2[nt][ci][r] + bias);
        }
        __syncthreads();
        // coalesced copy-out: 64 rows x 128 bf16
        for (int c = tid; c < 1024; c += 256) {
            int row = c >> 4, off = c & 15;
            int gn = n0blk + row;
            if (gn < N) {
                short8 v = *(const short8*)&hm[row * 136 + off * 8];
                *(short8*)&z1cat[(size_t)gn * 256 + br * 128 + off * 8] = v;
            }
        }
        __syncthreads();   // before branch t rewrites hm
    }
}

// ---------------- layer-2: gather + both-branch MLP fused in one kernel
// Staging phase = round-5 gather256 (32 lanes/node, uint4, unroll-4,
// sequential adds, f2bf at the same point) but writing into LDS hs instead
// of the agg2 buffer. MFMA body unchanged from round 5.
__global__ __launch_bounds__(256) void mlp2_kernel(
    const unsigned short* __restrict__ z1, const int* __restrict__ rowptr,
    const int* __restrict__ col, const unsigned short* __restrict__ pack,
    const float* __restrict__ b3s, const float* __restrict__ b4s,
    const float* __restrict__ b3t, const float* __restrict__ b4t,
    float* __restrict__ z2cat, int N)
{
    __shared__ __align__(16) unsigned short hs[64 * 264];
    __shared__ __align__(16) unsigned short hm[64 * 136];
    const int tid = threadIdx.x;
    const int n0blk = blockIdx.x * 64;

    // ---- gather-stage: 8 groups x 32 lanes, 8 rows per group ----
    {
        const int g = tid >> 5, l = tid & 31;
        const uint4* base = (const uint4*)z1;        // 32 uint4 per row
        for (int it = 0; it < 8; ++it) {
            int row = it * 8 + g;
            int gn = n0blk + row;
            float a0 = 0.f, a1 = 0.f, a2 = 0.f, a3 = 0.f;
            float a4 = 0.f, a5 = 0.f, a6 = 0.f, a7 = 0.f;
            if (gn < N) {
                uint4 s = base[(size_t)gn * 32 + l];     // self
                a0 = bflo(s.x); a1 = bfhi(s.x); a2 = bflo(s.y); a3 = bfhi(s.y);
                a4 = bflo(s.z); a5 = bfhi(s.z); a6 = bflo(s.w); a7 = bfhi(s.w);
                int b = rowptr[gn], e = rowptr[gn + 1];
                int i = b;
                for (; i + 4 <= e; i += 4) {
                    int s0 = col[i], s1 = col[i + 1], s2 = col[i + 2], s3 = col[i + 3];
                    uint4 v0 = base[(size_t)s0 * 32 + l];
                    uint4 v1 = base[(size_t)s1 * 32 + l];
                    uint4 v2 = base[(size_t)s2 * 32 + l];
                    uint4 v3 = base[(size_t)s3 * 32 + l];
                    a0 += bflo(v0.x); a1 += bfhi(v0.x); a2 += bflo(v0.y); a3 += bfhi(v0.y);
                    a4 += bflo(v0.z); a5 += bfhi(v0.z); a6 += bflo(v0.w); a7 += bfhi(v0.w);
                    a0 += bflo(v1.x); a1 += bfhi(v1.x); a2 += bflo(v1.y); a3 += bfhi(v1.y);
                    a4 += bflo(v1.z); a5 += bfhi(v1.z); a6 += bflo(v1.w); a7 += bfhi(v1.w);
                    a0 += bflo(v2.x); a1 += bfhi(v2.x); a2 += bflo(v2.y); a3 += bfhi(v2.y);
                    a4 += bflo(v2.z); a5 += bfhi(v2.z); a6 += bflo(v2.w); a7 += bfhi(v2.w);
                    a0 += bflo(v3.x); a1 += bfhi(v3.x); a2 += bflo(v3.y); a3 += bfhi(v3.y);
                    a4 += bflo(v3.z); a5 += bfhi(v3.z); a6 += bflo(v3.w); a7 += bfhi(v3.w);
                }
                for (; i + 2 <= e; i += 2) {
                    int s0 = col[i], s1 = col[i + 1];
                    uint4 v0 = base[(size_t)s0 * 32 + l];
                    uint4 v1 = base[(size_t)s1 * 32 + l];
                    a0 += bflo(v0.x); a1 += bfhi(v0.x); a2 += bflo(v0.y); a3 += bfhi(v0.y);
                    a4 += bflo(v0.z); a5 += bfhi(v0.z); a6 += bflo(v0.w); a7 += bfhi(v0.w);
                    a0 += bflo(v1.x); a1 += bfhi(v1.x); a2 += bflo(v1.y); a3 += bfhi(v1.y);
                    a4 += bflo(v1.z); a5 += bfhi(v1.z); a6 += bflo(v1.w); a7 += bfhi(v1.w);
                }
                for (; i < e; ++i) {
                    uint4 v0 = base[(size_t)col[i] * 32 + l];
                    a0 += bflo(v0.x); a1 += bfhi(v0.x); a2 += bflo(v0.y); a3 += bfhi(v0.y);
                    a4 += bflo(v0.z); a5 += bfhi(v0.z); a6 += bflo(v0.w); a7 += bfhi(v0.w);
                }
            }
            short8 st;
            st[0] = (short)f2bf(a0); st[1] = (short)f2bf(a1);
            st[2] = (short)f2bf(a2); st[3] = (short)f2bf(a3);
            st[4] = (short)f2bf(a4); st[5] = (short)f2bf(a5);
            st[6] = (short)f2bf(a6); st[7] = (short)f2bf(a7);
            *(short8*)&hs[row * 264 + l * 8] = st;
        }
    }
    __syncthreads();

    const int wv = tid >> 6, l = tid & 63, q = l >> 4, m = l & 15;

    for (int br = 0; br < 2; ++br) {
        const int w1off = br ? W3T_OFF : W3S_OFF;
        const int w2off = br ? W4T_OFF : W4S_OFF;
        const float* B1 = br ? b3t : b3s;
        const float* B2 = br ? b4t : b4s;
        if (br) __syncthreads();   // br0 stage2 hm reads done before rewrite

        // ---- stage 1: hm = relu(hs[:, br*128..] @ W3 + b3), K=128 ----
        for (int nt = 0; nt < 4; ++nt) {
            short8 a[4];
            #pragma unroll
            for (int kt = 0; kt < 4; ++kt)
                a[kt] = *(const short8*)&hs[(nt * 16 + m) * 264 + br * 128 + kt * 32 + q * 8];
            #pragma unroll
            for (int ci = 0; ci < 2; ++ci) {
                int ct = wv * 2 + ci;
                f32x4 acc = {0.f, 0.f, 0.f, 0.f};
                #pragma unroll
                for (int kt = 0; kt < 4; ++kt) {
                    short8 bf = *(const short8*)&pack[w1off + ((size_t)(ct * 4 + kt) * 64 + l) * 8];
                    acc = __builtin_amdgcn_mfma_f32_16x16x32_bf16(a[kt], bf, acc, 0, 0, 0);
                }
                float bias = B1[ct * 16 + m];
                #pragma unroll
                for (int r = 0; r < 4; ++r) {
                    float v = fmaxf(acc[r] + bias, 0.f);
                    hm[(nt * 16 + q * 4 + r) * 136 + ct * 16 + m] = f2bf(v);
                }
            }
        }
        __syncthreads();

        // ---- stage 2: z2cat slice = hm @ W4 + b4 (64 cols, 1 ct/wave) ----
        {
            int ct = wv;
            float bias = B2[ct * 16 + m];
            for (int nt = 0; nt < 4; ++nt) {
                short8 a[4];
                #pragma unroll
                for (int kt = 0; kt < 4; ++kt)
                    a[kt] = *(const short8*)&hm[(nt * 16 + m) * 136 + kt * 32 + q * 8];
                f32x4 acc = {0.f, 0.f, 0.f, 0.f};
                #pragma unroll
                for (int kt = 0; kt < 4; ++kt) {
                    short8 bf = *(const short8*)&pack[w2off + ((size_t)(ct * 4 + kt) * 64 + l) * 8];
                    acc = __builtin_amdgcn_mfma_f32_16x16x32_bf16(a[kt], bf, acc, 0, 0, 0);
                }
                #pragma unroll
                for (int r = 0; r < 4; ++r) {
                    int gn = n0blk + nt * 16 + q * 4 + r;
                    if (gn < N)
                        z2cat[(size_t)gn * 128 + br * 64 + ct * 16 + m] = acc[r] + bias;
                }
            }
        }
    }
}

// ---------------- per-graph 9x9 gram from z2cat [N,128] (s=0..63,t=64..127)
__global__ __launch_bounds__(128) void einsum9_kernel(
    const float* __restrict__ z2cat, float* __restrict__ out, int G)
{
    int g = blockIdx.x;
    if (g >= G) return;
    __shared__ float ss[9][68];
    __shared__ float tt[9][68];
    const int tid = threadIdx.x;
    for (int idx = tid; idx < 9 * 64; idx += 128) {
        int n = idx >> 6, k = idx & 63;
        size_t row = (size_t)(g * 9 + n) * 128;
        ss[n][k] = z2cat[row + k];
        tt[n][k] = z2cat[row + 64 + k];
    }
    __syncthreads();
    if (tid < 81) {
        int i = tid / 9, j = tid - 9 * (tid / 9);
        float acc = 0.f;
        #pragma unroll
        for (int k = 0; k < 64; ++k) acc += ss[i][k] * tt[j][k];
        out[(size_t)g * 81 + i * 9 + j] = acc;
    }
}

extern "C" void kernel_launch(void* const* d_in, const int* in_sizes, int n_in,
                              void* d_out, int out_size, void* d_ws, size_t ws_size,
                              hipStream_t stream)
{
    const float* x  = (const float*)d_in[0];
    const int*   ei = (const int*)d_in[1];
    const int N_ = in_sizes[0] / 30;
    const int E_ = in_sizes[1] / 2;
    const int* src = ei;
    const int* dst = ei + E_;

    const float* w1s = (const float*)d_in[2];
    const float* b1s = (const float*)d_in[3];
    const float* w2s = (const float*)d_in[4];
    const float* b2s = (const float*)d_in[5];
    const float* w3s = (const float*)d_in[6];
    const float* b3s = (const float*)d_in[7];
    const float* w4s = (const float*)d_in[8];
    const float* b4s = (const float*)d_in[9];
    const float* w1t = (const float*)d_in[10];
    const float* b1t = (const float*)d_in[11];
    const float* w2t = (const float*)d_in[12];
    const float* b2t = (const float*)d_in[13];
    const float* w3t = (const float*)d_in[14];
    const float* b3t = (const float*)d_in[15];
    const float* w4t = (const float*)d_in[16];
    const float* b4t = (const float*)d_in[17];

    // ---- workspace layout ----
    int* deg    = (int*)d_ws;               // N
    int* rowptr = deg + N_;                 // N+1
    int* cursor = rowptr + N_ + 1;          // N
    int* bsum   = cursor + N_;              // 1024
    int* boff   = bsum + 1024;              // 1024
    int* col    = boff + 1024;              // E
    size_t int_bytes = ((size_t)3 * N_ + 1 + 2048 + (size_t)E_) * sizeof(int);
    size_t pb = (int_bytes + 15) & ~(size_t)15;
    unsigned short* packu = (unsigned short*)((char*)d_ws + pb);
    float* xpad = (float*)(packu + PACK_USHORTS);         // [N,32] fp32
    unsigned short* h1    = (unsigned short*)(xpad + (size_t)N_ * 32); // [N,32] bf16
    unsigned short* z1cat = h1 + (size_t)N_ * 32;         // [N,256] bf16 s||t
    float* z2cat = (float*)(z1cat + (size_t)N_ * 256);    // [N,128] fp32 s||t
    size_t need = pb + (size_t)PACK_USHORTS * 2
                + (size_t)N_ * 32 * 4            // xpad
                + (size_t)N_ * 32 * 2            // h1
                + (size_t)N_ * 256 * 2           // z1cat
                + (size_t)N_ * 128 * 4;          // z2cat
    if (ws_size < need) return;

    const int nbE   = (E_ + 255) / 256;
    const int nb256 = (N_ + 255) / 256;
    const int nb64  = (N_ + 63) / 64;
    if (nb256 > 1024) return;   // single-block scan capacity

    // ---- weight packing + x padding (independent of CSR) ----
    wpack_kernel<<<176, 64, 0, stream>>>(w1s, w2s, w3s, w4s,
                                         w1t, w2t, w3t, w4t, packu);
    xpad_kernel<<<(N_ * 32 + 255) / 256, 256, 0, stream>>>(x, xpad, N_);

    // ---- CSR build ----
    hipMemsetAsync(deg, 0, (size_t)N_ * sizeof(int), stream);
    hist_kernel<<<nbE, 256, 0, stream>>>(dst, deg, E_);
    blocksum_kernel<<<nb256, 256, 0, stream>>>(deg, bsum, N_);
    scanblock_kernel<<<1, 1024, 0, stream>>>(bsum, boff, nb256);
    rowptr_kernel<<<nb256, 256, 0, stream>>>(deg, boff, rowptr, cursor, N_, E_);
    scatter_kernel<<<nbE, 256, 0, stream>>>(src, dst, cursor, col, E_);

    // ---- layer-1 aggregation: 8 lanes/node float4 gather -> bf16 h1 ----
    gather30_kernel<<<(N_ * 8 + 255) / 256, 256, 0, stream>>>(
        xpad, rowptr, col, h1, N_);

    // ---- layer 1: both branches (MFMA), writes bf16 z1cat ----
    mlp1_kernel<<<nb64, 256, 0, stream>>>(h1, packu,
        b1s, b2s, b1t, b2t, z1cat, N_);

    // ---- layer 2: gather + both branches fused (MFMA) ----
    mlp2_kernel<<<nb64, 256, 0, stream>>>(z1cat, rowptr, col, packu,
        b3s, b4s, b3t, b4t, z2cat, N_);

    // ---- per-graph 9x9 gram ----
    einsum9_kernel<<<N_ / 9, 128, 0, stream>>>(z2cat, (float*)d_out, N_ / 9);
}

// Round 7
// 277.158 us; speedup vs baseline: 3.5039x; 1.0573x over previous
//
#include <hip/hip_runtime.h>
#include <hip/hip_bf16.h>

// GIN x2 layers x2 branches + per-graph 9x9 gram einsum.
// Round 7: mlp2 -> 512-thread blocks (same 64-node tile, same LDS) to double
// gather-phase waves/CU (12 -> 24); stage-1 1 col-tile/wave, stage-2 split
// across 8 waves. deg-zeroing folded into xpad kernel. All arithmetic
// sequences unchanged -> absmax must stay exactly 14.5.

typedef __attribute__((ext_vector_type(8))) short short8;
typedef __attribute__((ext_vector_type(4))) float f32x4;

__device__ inline unsigned short f2bf(float f) {
    union { float f; unsigned u; } v; v.f = f;
    unsigned r = v.u + 0x7fffu + ((v.u >> 16) & 1u);   // RNE
    return (unsigned short)(r >> 16);
}
__device__ inline float bflo(unsigned u) { return __uint_as_float(u << 16); }
__device__ inline float bfhi(unsigned u) { return __uint_as_float(u & 0xffff0000u); }
__device__ inline unsigned packbf(float a, float b) {
    return (unsigned)f2bf(a) | ((unsigned)f2bf(b) << 16);
}

// pack offsets (ushort units): [w1s][w2s][w3s][w4s][w1t][w2t][w3t][w4t]
#define W1S_OFF 0
#define W2S_OFF 4096
#define W3S_OFF 20480
#define W4S_OFF 36864
#define W1T_OFF 45056
#define W2T_OFF 49152
#define W3T_OFF 65536
#define W4T_OFF 81920
#define PACK_USHORTS 90112

// ---------------------------------------------------------------- CSR build
__global__ __launch_bounds__(256) void hist_kernel(
    const int* __restrict__ dst, int* __restrict__ deg, int E)
{
    int e = blockIdx.x * 256 + threadIdx.x;
    if (e < E) atomicAdd(&deg[dst[e]], 1);
}

__global__ __launch_bounds__(256) void blocksum_kernel(
    const int* __restrict__ deg, int* __restrict__ bsum, int N)
{
    __shared__ int sh[256];
    int i = blockIdx.x * 256 + threadIdx.x;
    sh[threadIdx.x] = (i < N) ? deg[i] : 0;
    __syncthreads();
    for (int off = 128; off > 0; off >>= 1) {
        if (threadIdx.x < off) sh[threadIdx.x] += sh[threadIdx.x + off];
        __syncthreads();
    }
    if (threadIdx.x == 0) bsum[blockIdx.x] = sh[0];
}

__global__ __launch_bounds__(1024) void scanblock_kernel(
    const int* __restrict__ bsum, int* __restrict__ boff, int nb)
{
    __shared__ int sh[1024];
    int t = threadIdx.x;
    int v = (t < nb) ? bsum[t] : 0;
    sh[t] = v;
    __syncthreads();
    for (int off = 1; off < 1024; off <<= 1) {
        int a = (t >= off) ? sh[t - off] : 0;
        __syncthreads();
        sh[t] += a;
        __syncthreads();
    }
    if (t < nb) boff[t] = sh[t] - v;   // exclusive
}

__global__ __launch_bounds__(256) void rowptr_kernel(
    const int* __restrict__ deg, const int* __restrict__ boff,
    int* __restrict__ rowptr, int* __restrict__ cursor, int N, int E)
{
    __shared__ int sh[256];
    int t = threadIdx.x;
    int i = blockIdx.x * 256 + t;
    int v = (i < N) ? deg[i] : 0;
    sh[t] = v;
    __syncthreads();
    for (int off = 1; off < 256; off <<= 1) {
        int a = (t >= off) ? sh[t - off] : 0;
        __syncthreads();
        sh[t] += a;
        __syncthreads();
    }
    if (i < N) {
        int r = boff[blockIdx.x] + sh[t] - v;
        rowptr[i] = r;
        cursor[i] = r;
    }
    if (i == 0) rowptr[N] = E;
}

__global__ __launch_bounds__(256) void scatter_kernel(
    const int* __restrict__ src, const int* __restrict__ dst,
    int* __restrict__ cursor, int* __restrict__ col, int E)
{
    int e = blockIdx.x * 256 + threadIdx.x;
    if (e < E) {
        int d = dst[e];
        int pos = atomicAdd(&cursor[d], 1);
        col[pos] = src[e];
    }
}

// ------------------------------------------------------------ weight packer
// B-frag order for 16x16x32 bf16 (m89/m91-verified): lane l holds
// B[k = kt*32 + (l>>4)*8 + j][n = ct*16 + (l&15)], j=0..7 contiguous.
__global__ __launch_bounds__(64) void wpack_kernel(
    const float* w0, const float* w1, const float* w2, const float* w3,
    const float* w4, const float* w5, const float* w6, const float* w7,
    unsigned short* __restrict__ pack)
{
    const int prefix[9] = {0, 8, 40, 72, 88, 96, 128, 160, 176};
    const int KTa[8] = {1, 4, 4, 4, 1, 4, 4, 4};
    const int KRa[8] = {30, 128, 128, 128, 30, 128, 128, 128};
    const int Ca[8]  = {128, 128, 128, 64, 128, 128, 128, 64};
    const int DOFF[8] = {W1S_OFF, W2S_OFF, W3S_OFF, W4S_OFF,
                         W1T_OFF, W2T_OFF, W3T_OFF, W4T_OFF};
    const float* Ws[8] = {w0, w1, w2, w3, w4, w5, w6, w7};
    int bid = blockIdx.x;
    int mi = 0;
    while (mi < 7 && bid >= prefix[mi + 1]) ++mi;
    int lt = bid - prefix[mi];
    int kt = lt % KTa[mi], ct = lt / KTa[mi];
    const float* W = Ws[mi];
    int l = threadIdx.x;
    int n = ct * 16 + (l & 15);
    for (int j = 0; j < 8; ++j) {
        int k = kt * 32 + (l >> 4) * 8 + j;
        float v = (k < KRa[mi]) ? W[(size_t)k * Ca[mi] + n] : 0.f;
        pack[(size_t)DOFF[mi] + (size_t)lt * 512 + l * 8 + j] = f2bf(v);
    }
}

// ---------------------------- x padding (fp32 exact) + deg zeroing (fused)
__global__ __launch_bounds__(256) void xpad_zero_kernel(
    const float* __restrict__ x, float* __restrict__ xpad,
    int* __restrict__ deg, int N)
{
    int gid = blockIdx.x * 256 + threadIdx.x;
    if (gid < N) deg[gid] = 0;
    if (gid >= N * 32) return;
    int n = gid >> 5, f = gid & 31;
    xpad[gid] = (f < 30) ? x[(size_t)n * 30 + f] : 0.f;
}

// ------------------------------------------- layer-1 aggregation (gather)
// 8 lanes/node, float4 (16B) per lane over xpad[N,32] fp32. Per-feature
// sequential add order identical to prior rounds -> bit-identical h1.
__global__ __launch_bounds__(256) void gather30_kernel(
    const float* __restrict__ xpad, const int* __restrict__ rowptr,
    const int* __restrict__ col, unsigned short* __restrict__ h1, int N)
{
    int gid = blockIdx.x * 256 + threadIdx.x;
    int node = gid >> 3;
    if (node >= N) return;
    int l = gid & 7;
    const float4* base = (const float4*)xpad;   // 8 float4 per row
    float4 a = base[(size_t)node * 8 + l];      // self (exact fp32)
    int b = rowptr[node], e = rowptr[node + 1];
    int i = b;
    for (; i + 4 <= e; i += 4) {
        int s0 = col[i], s1 = col[i + 1], s2 = col[i + 2], s3 = col[i + 3];
        float4 v0 = base[(size_t)s0 * 8 + l];
        float4 v1 = base[(size_t)s1 * 8 + l];
        float4 v2 = base[(size_t)s2 * 8 + l];
        float4 v3 = base[(size_t)s3 * 8 + l];
        a.x += v0.x; a.y += v0.y; a.z += v0.z; a.w += v0.w;
        a.x += v1.x; a.y += v1.y; a.z += v1.z; a.w += v1.w;
        a.x += v2.x; a.y += v2.y; a.z += v2.z; a.w += v2.w;
        a.x += v3.x; a.y += v3.y; a.z += v3.z; a.w += v3.w;
    }
    for (; i + 2 <= e; i += 2) {
        int s0 = col[i], s1 = col[i + 1];
        float4 v0 = base[(size_t)s0 * 8 + l];
        float4 v1 = base[(size_t)s1 * 8 + l];
        a.x += v0.x; a.y += v0.y; a.z += v0.z; a.w += v0.w;
        a.x += v1.x; a.y += v1.y; a.z += v1.z; a.w += v1.w;
    }
    for (; i < e; ++i) {
        float4 v0 = base[(size_t)col[i] * 8 + l];
        a.x += v0.x; a.y += v0.y; a.z += v0.z; a.w += v0.w;
    }
    uint2 o; o.x = packbf(a.x, a.y); o.y = packbf(a.z, a.w);
    ((uint2*)h1)[(size_t)node * 8 + l] = o;
}

// ------------------------------------------------- layer-1 MLP (dual branch)
__global__ __launch_bounds__(256) void mlp1_kernel(
    const unsigned short* __restrict__ h1, const unsigned short* __restrict__ pack,
    const float* __restrict__ b1s, const float* __restrict__ b2s,
    const float* __restrict__ b1t, const float* __restrict__ b2t,
    unsigned short* __restrict__ z1cat, int N)
{
    __shared__ __align__(16) unsigned short hs[64 * 40];
    __shared__ __align__(16) unsigned short hm[64 * 136];
    const int tid = threadIdx.x;
    const int n0blk = blockIdx.x * 64;

    // ---- stage h1 rows (32 bf16 each), coalesced 16B/thread ----
    {
        int row = tid >> 2, off = tid & 3;
        int gn = n0blk + row;
        short8 v = {0, 0, 0, 0, 0, 0, 0, 0};
        if (gn < N) v = *(const short8*)&h1[(size_t)gn * 32 + off * 8];
        *(short8*)&hs[row * 40 + off * 8] = v;
    }
    __syncthreads();

    const int wv = tid >> 6, l = tid & 63, q = l >> 4, m = l & 15;

    for (int br = 0; br < 2; ++br) {
        const float* B1 = br ? b1t : b1s;
        const float* B2 = br ? b2t : b2s;
        const int w1off = br ? W1T_OFF : W1S_OFF;
        const int w2off = br ? W2T_OFF : W2S_OFF;

        // ---- stage 1: hm = relu(h1 @ W1 + b1), K=32 single MFMA ----
        {
            short8 a[4];
            #pragma unroll
            for (int nt = 0; nt < 4; ++nt)
                a[nt] = *(const short8*)&hs[(nt * 16 + m) * 40 + q * 8];
            #pragma unroll
            for (int ci = 0; ci < 2; ++ci) {
                int ct = wv * 2 + ci;
                short8 bf = *(const short8*)&pack[w1off + ((size_t)ct * 64 + l) * 8];
                float bias = B1[ct * 16 + m];
                #pragma unroll
                for (int nt = 0; nt < 4; ++nt) {
                    f32x4 acc = {0.f, 0.f, 0.f, 0.f};
                    acc = __builtin_amdgcn_mfma_f32_16x16x32_bf16(a[nt], bf, acc, 0, 0, 0);
                    #pragma unroll
                    for (int r = 0; r < 4; ++r) {
                        float v = fmaxf(acc[r] + bias, 0.f);
                        hm[(nt * 16 + q * 4 + r) * 136 + ct * 16 + m] = f2bf(v);
                    }
                }
            }
        }
        __syncthreads();

        // ---- stage 2: z1 = hm @ W2 + b2 (K=128), defer writeback ----
        f32x4 acc2[4][2];
        #pragma unroll
        for (int nt = 0; nt < 4; ++nt)
            #pragma unroll
            for (int ci = 0; ci < 2; ++ci)
                acc2[nt][ci] = (f32x4){0.f, 0.f, 0.f, 0.f};
        for (int nt = 0; nt < 4; ++nt) {
            short8 a[4];
            #pragma unroll
            for (int kt = 0; kt < 4; ++kt)
                a[kt] = *(const short8*)&hm[(nt * 16 + m) * 136 + kt * 32 + q * 8];
            #pragma unroll
            for (int ci = 0; ci < 2; ++ci) {
                int ct = wv * 2 + ci;
                #pragma unroll
                for (int kt = 0; kt < 4; ++kt) {
                    short8 bf = *(const short8*)&pack[w2off + ((size_t)(ct * 4 + kt) * 64 + l) * 8];
                    acc2[nt][ci] = __builtin_amdgcn_mfma_f32_16x16x32_bf16(a[kt], bf, acc2[nt][ci], 0, 0, 0);
                }
            }
        }
        __syncthreads();   // all hm A-frag reads complete
        #pragma unroll
        for (int ci = 0; ci < 2; ++ci) {
            int ct = wv * 2 + ci;
            float bias = B2[ct * 16 + m];
            #pragma unroll
            for (int nt = 0; nt < 4; ++nt)
                #pragma unroll
                for (int r = 0; r < 4; ++r)
                    hm[(nt * 16 + q * 4 + r) * 136 + ct * 16 + m] =
                        f2bf(acc2[nt][ci][r] + bias);
        }
        __syncthreads();
        // coalesced copy-out: 64 rows x 128 bf16
        for (int c = tid; c < 1024; c += 256) {
            int row = c >> 4, off = c & 15;
            int gn = n0blk + row;
            if (gn < N) {
                short8 v = *(const short8*)&hm[row * 136 + off * 8];
                *(short8*)&z1cat[(size_t)gn * 256 + br * 128 + off * 8] = v;
            }
        }
        __syncthreads();   // before branch t rewrites hm
    }
}

// ---------------- layer-2: gather + both-branch MLP fused (512 threads)
// Gather phase: 16 groups x 32 lanes, 4 rows/group (row body byte-identical
// to round 6). MFMA: stage1 ct=wv (8 waves x 8 col-tiles); stage2 ct=wv&3,
// 2 node-tiles per wave. Per-accumulator MFMA sequences unchanged.
__global__ __launch_bounds__(512, 6) void mlp2_kernel(
    const unsigned short* __restrict__ z1, const int* __restrict__ rowptr,
    const int* __restrict__ col, const unsigned short* __restrict__ pack,
    const float* __restrict__ b3s, const float* __restrict__ b4s,
    const float* __restrict__ b3t, const float* __restrict__ b4t,
    float* __restrict__ z2cat, int N)
{
    __shared__ __align__(16) unsigned short hs[64 * 264];
    __shared__ __align__(16) unsigned short hm[64 * 136];
    const int tid = threadIdx.x;
    const int n0blk = blockIdx.x * 64;

    // ---- gather-stage: 16 groups x 32 lanes, 4 rows per group ----
    {
        const int g = tid >> 5, l = tid & 31;
        const uint4* base = (const uint4*)z1;        // 32 uint4 per row
        for (int it = 0; it < 4; ++it) {
            int row = it * 16 + g;
            int gn = n0blk + row;
            float a0 = 0.f, a1 = 0.f, a2 = 0.f, a3 = 0.f;
            float a4 = 0.f, a5 = 0.f, a6 = 0.f, a7 = 0.f;
            if (gn < N) {
                uint4 s = base[(size_t)gn * 32 + l];     // self
                a0 = bflo(s.x); a1 = bfhi(s.x); a2 = bflo(s.y); a3 = bfhi(s.y);
                a4 = bflo(s.z); a5 = bfhi(s.z); a6 = bflo(s.w); a7 = bfhi(s.w);
                int b = rowptr[gn], e = rowptr[gn + 1];
                int i = b;
                for (; i + 4 <= e; i += 4) {
                    int s0 = col[i], s1 = col[i + 1], s2 = col[i + 2], s3 = col[i + 3];
                    uint4 v0 = base[(size_t)s0 * 32 + l];
                    uint4 v1 = base[(size_t)s1 * 32 + l];
                    uint4 v2 = base[(size_t)s2 * 32 + l];
                    uint4 v3 = base[(size_t)s3 * 32 + l];
                    a0 += bflo(v0.x); a1 += bfhi(v0.x); a2 += bflo(v0.y); a3 += bfhi(v0.y);
                    a4 += bflo(v0.z); a5 += bfhi(v0.z); a6 += bflo(v0.w); a7 += bfhi(v0.w);
                    a0 += bflo(v1.x); a1 += bfhi(v1.x); a2 += bflo(v1.y); a3 += bfhi(v1.y);
                    a4 += bflo(v1.z); a5 += bfhi(v1.z); a6 += bflo(v1.w); a7 += bfhi(v1.w);
                    a0 += bflo(v2.x); a1 += bfhi(v2.x); a2 += bflo(v2.y); a3 += bfhi(v2.y);
                    a4 += bflo(v2.z); a5 += bfhi(v2.z); a6 += bflo(v2.w); a7 += bfhi(v2.w);
                    a0 += bflo(v3.x); a1 += bfhi(v3.x); a2 += bflo(v3.y); a3 += bfhi(v3.y);
                    a4 += bflo(v3.z); a5 += bfhi(v3.z); a6 += bflo(v3.w); a7 += bfhi(v3.w);
                }
                for (; i + 2 <= e; i += 2) {
                    int s0 = col[i], s1 = col[i + 1];
                    uint4 v0 = base[(size_t)s0 * 32 + l];
                    uint4 v1 = base[(size_t)s1 * 32 + l];
                    a0 += bflo(v0.x); a1 += bfhi(v0.x); a2 += bflo(v0.y); a3 += bfhi(v0.y);
                    a4 += bflo(v0.z); a5 += bfhi(v0.z); a6 += bflo(v0.w); a7 += bfhi(v0.w);
                    a0 += bflo(v1.x); a1 += bfhi(v1.x); a2 += bflo(v1.y); a3 += bfhi(v1.y);
                    a4 += bflo(v1.z); a5 += bfhi(v1.z); a6 += bflo(v1.w); a7 += bfhi(v1.w);
                }
                for (; i < e; ++i) {
                    uint4 v0 = base[(size_t)col[i] * 32 + l];
                    a0 += bflo(v0.x); a1 += bfhi(v0.x); a2 += bflo(v0.y); a3 += bfhi(v0.y);
                    a4 += bflo(v0.z); a5 += bfhi(v0.z); a6 += bflo(v0.w); a7 += bfhi(v0.w);
                }
            }
            short8 st;
            st[0] = (short)f2bf(a0); st[1] = (short)f2bf(a1);
            st[2] = (short)f2bf(a2); st[3] = (short)f2bf(a3);
            st[4] = (short)f2bf(a4); st[5] = (short)f2bf(a5);
            st[6] = (short)f2bf(a6); st[7] = (short)f2bf(a7);
            *(short8*)&hs[row * 264 + l * 8] = st;
        }
    }
    __syncthreads();

    const int wv = tid >> 6, l = tid & 63, q = l >> 4, m = l & 15;

    for (int br = 0; br < 2; ++br) {
        const int w1off = br ? W3T_OFF : W3S_OFF;
        const int w2off = br ? W4T_OFF : W4S_OFF;
        const float* B1 = br ? b3t : b3s;
        const float* B2 = br ? b4t : b4s;
        if (br) __syncthreads();   // br0 stage2 hm reads done before rewrite

        // ---- stage 1: hm = relu(hs[:, br*128..] @ W3 + b3), K=128 ----
        {
            const int ct = wv;     // one col-tile per wave (8 waves, 8 tiles)
            float bias = B1[ct * 16 + m];
            for (int nt = 0; nt < 4; ++nt) {
                short8 a[4];
                #pragma unroll
                for (int kt = 0; kt < 4; ++kt)
                    a[kt] = *(const short8*)&hs[(nt * 16 + m) * 264 + br * 128 + kt * 32 + q * 8];
                f32x4 acc = {0.f, 0.f, 0.f, 0.f};
                #pragma unroll
                for (int kt = 0; kt < 4; ++kt) {
                    short8 bf = *(const short8*)&pack[w1off + ((size_t)(ct * 4 + kt) * 64 + l) * 8];
                    acc = __builtin_amdgcn_mfma_f32_16x16x32_bf16(a[kt], bf, acc, 0, 0, 0);
                }
                #pragma unroll
                for (int r = 0; r < 4; ++r) {
                    float v = fmaxf(acc[r] + bias, 0.f);
                    hm[(nt * 16 + q * 4 + r) * 136 + ct * 16 + m] = f2bf(v);
                }
            }
        }
        __syncthreads();

        // ---- stage 2: z2cat slice = hm @ W4 + b4 (4 col-tiles x 4 nt,
        //      wave wv -> ct=wv&3, nt in {2*(wv>>2), 2*(wv>>2)+1}) ----
        {
            const int ct = wv & 3;
            const int ntb = (wv >> 2) * 2;
            float bias = B2[ct * 16 + m];
            for (int ni = 0; ni < 2; ++ni) {
                int nt = ntb + ni;
                short8 a[4];
                #pragma unroll
                for (int kt = 0; kt < 4; ++kt)
                    a[kt] = *(const short8*)&hm[(nt * 16 + m) * 136 + kt * 32 + q * 8];
                f32x4 acc = {0.f, 0.f, 0.f, 0.f};
                #pragma unroll
                for (int kt = 0; kt < 4; ++kt) {
                    short8 bf = *(const short8*)&pack[w2off + ((size_t)(ct * 4 + kt) * 64 + l) * 8];
                    acc = __builtin_amdgcn_mfma_f32_16x16x32_bf16(a[kt], bf, acc, 0, 0, 0);
                }
                #pragma unroll
                for (int r = 0; r < 4; ++r) {
                    int gn = n0blk + nt * 16 + q * 4 + r;
                    if (gn < N)
                        z2cat[(size_t)gn * 128 + br * 64 + ct * 16 + m] = acc[r] + bias;
                }
            }
        }
    }
}

// ---------------- per-graph 9x9 gram from z2cat [N,128] (s=0..63,t=64..127)
__global__ __launch_bounds__(128) void einsum9_kernel(
    const float* __restrict__ z2cat, float* __restrict__ out, int G)
{
    int g = blockIdx.x;
    if (g >= G) return;
    __shared__ float ss[9][68];
    __shared__ float tt[9][68];
    const int tid = threadIdx.x;
    for (int idx = tid; idx < 9 * 64; idx += 128) {
        int n = idx >> 6, k = idx & 63;
        size_t row = (size_t)(g * 9 + n) * 128;
        ss[n][k] = z2cat[row + k];
        tt[n][k] = z2cat[row + 64 + k];
    }
    __syncthreads();
    if (tid < 81) {
        int i = tid / 9, j = tid - 9 * (tid / 9);
        float acc = 0.f;
        #pragma unroll
        for (int k = 0; k < 64; ++k) acc += ss[i][k] * tt[j][k];
        out[(size_t)g * 81 + i * 9 + j] = acc;
    }
}

extern "C" void kernel_launch(void* const* d_in, const int* in_sizes, int n_in,
                              void* d_out, int out_size, void* d_ws, size_t ws_size,
                              hipStream_t stream)
{
    const float* x  = (const float*)d_in[0];
    const int*   ei = (const int*)d_in[1];
    const int N_ = in_sizes[0] / 30;
    const int E_ = in_sizes[1] / 2;
    const int* src = ei;
    const int* dst = ei + E_;

    const float* w1s = (const float*)d_in[2];
    const float* b1s = (const float*)d_in[3];
    const float* w2s = (const float*)d_in[4];
    const float* b2s = (const float*)d_in[5];
    const float* w3s = (const float*)d_in[6];
    const float* b3s = (const float*)d_in[7];
    const float* w4s = (const float*)d_in[8];
    const float* b4s = (const float*)d_in[9];
    const float* w1t = (const float*)d_in[10];
    const float* b1t = (const float*)d_in[11];
    const float* w2t = (const float*)d_in[12];
    const float* b2t = (const float*)d_in[13];
    const float* w3t = (const float*)d_in[14];
    const float* b3t = (const float*)d_in[15];
    const float* w4t = (const float*)d_in[16];
    const float* b4t = (const float*)d_in[17];

    // ---- workspace layout ----
    int* deg    = (int*)d_ws;               // N
    int* rowptr = deg + N_;                 // N+1
    int* cursor = rowptr + N_ + 1;          // N
    int* bsum   = cursor + N_;              // 1024
    int* boff   = bsum + 1024;              // 1024
    int* col    = boff + 1024;              // E
    size_t int_bytes = ((size_t)3 * N_ + 1 + 2048 + (size_t)E_) * sizeof(int);
    size_t pb = (int_bytes + 15) & ~(size_t)15;
    unsigned short* packu = (unsigned short*)((char*)d_ws + pb);
    float* xpad = (float*)(packu + PACK_USHORTS);         // [N,32] fp32
    unsigned short* h1    = (unsigned short*)(xpad + (size_t)N_ * 32); // [N,32] bf16
    unsigned short* z1cat = h1 + (size_t)N_ * 32;         // [N,256] bf16 s||t
    float* z2cat = (float*)(z1cat + (size_t)N_ * 256);    // [N,128] fp32 s||t
    size_t need = pb + (size_t)PACK_USHORTS * 2
                + (size_t)N_ * 32 * 4            // xpad
                + (size_t)N_ * 32 * 2            // h1
                + (size_t)N_ * 256 * 2           // z1cat
                + (size_t)N_ * 128 * 4;          // z2cat
    if (ws_size < need) return;

    const int nbE   = (E_ + 255) / 256;
    const int nb256 = (N_ + 255) / 256;
    const int nb64  = (N_ + 63) / 64;
    if (nb256 > 1024) return;   // single-block scan capacity

    // ---- weight packing + x padding + deg zeroing (independent of CSR) ----
    wpack_kernel<<<176, 64, 0, stream>>>(w1s, w2s, w3s, w4s,
                                         w1t, w2t, w3t, w4t, packu);
    xpad_zero_kernel<<<(N_ * 32 + 255) / 256, 256, 0, stream>>>(x, xpad, deg, N_);

    // ---- CSR build ----
    hist_kernel<<<nbE, 256, 0, stream>>>(dst, deg, E_);
    blocksum_kernel<<<nb256, 256, 0, stream>>>(deg, bsum, N_);
    scanblock_kernel<<<1, 1024, 0, stream>>>(bsum, boff, nb256);
    rowptr_kernel<<<nb256, 256, 0, stream>>>(deg, boff, rowptr, cursor, N_, E_);
    scatter_kernel<<<nbE, 256, 0, stream>>>(src, dst, cursor, col, E_);

    // ---- layer-1 aggregation: 8 lanes/node float4 gather -> bf16 h1 ----
    gather30_kernel<<<(N_ * 8 + 255) / 256, 256, 0, stream>>>(
        xpad, rowptr, col, h1, N_);

    // ---- layer 1: both branches (MFMA), writes bf16 z1cat ----
    mlp1_kernel<<<nb64, 256, 0, stream>>>(h1, packu,
        b1s, b2s, b1t, b2t, z1cat, N_);

    // ---- layer 2: gather + both branches fused (MFMA, 512 threads) ----
    mlp2_kernel<<<nb64, 512, 0, stream>>>(z1cat, rowptr, col, packu,
        b3s, b4s, b3t, b4t, z2cat, N_);

    // ---- per-graph 9x9 gram ----
    einsum9_kernel<<<N_ / 9, 128, 0, stream>>>(z2cat, (float*)d_out, N_ / 9);
}